// Round 1
// baseline (774.684 us; speedup 1.0000x reference)
//
#include <hip/hip_runtime.h>
#include <hip/hip_bf16.h>
#include <math.h>

#define GG 8192
#define AA 5
#define NN (GG * AA)        // 40960
#define DD 512
#define HEADS_ 8
#define HID_ 64

// ---------------------------------------------------------------------------
// K1: h1pre = x @ W1  (no bias), fused per-head scores ss/sd.
// 4 nodes per block, 512 threads (one output column per thread).
// ---------------------------------------------------------------------------
__global__ __launch_bounds__(512) void k1_inproj(
    const float* __restrict__ x, const float* __restrict__ W1,
    const float* __restrict__ as1, const float* __restrict__ ad1,
    float* __restrict__ hpre, float* __restrict__ ss, float* __restrict__ sd) {
  int n0 = blockIdx.x * 4;
  int t = threadIdx.x;
  __shared__ float sx[116];
  if (t < 116) sx[t] = x[(size_t)n0 * 29 + t];
  __syncthreads();
  float acc0 = 0.f, acc1 = 0.f, acc2 = 0.f, acc3 = 0.f;
  float a_s = as1[t], a_d = ad1[t];
#pragma unroll
  for (int k = 0; k < 29; ++k) {
    float w = W1[k * 512 + t];
    acc0 = fmaf(sx[k], w, acc0);
    acc1 = fmaf(sx[29 + k], w, acc1);
    acc2 = fmaf(sx[58 + k], w, acc2);
    acc3 = fmaf(sx[87 + k], w, acc3);
  }
  float accs[4] = {acc0, acc1, acc2, acc3};
#pragma unroll
  for (int v = 0; v < 4; ++v) {
    hpre[(size_t)(n0 + v) * 512 + t] = accs[v];
    float vs = accs[v] * a_s;
    float vd = accs[v] * a_d;
#pragma unroll
    for (int o = 32; o > 0; o >>= 1) {
      vs += __shfl_xor(vs, o);
      vd += __shfl_xor(vd, o);
    }
    if ((t & 63) == 0) {
      ss[(size_t)(n0 + v) * 8 + (t >> 6)] = vs;
      sd[(size_t)(n0 + v) * 8 + (t >> 6)] = vd;
    }
  }
}

// ---------------------------------------------------------------------------
// scores only (for layer 2): ss/sd from hpre
// ---------------------------------------------------------------------------
__global__ __launch_bounds__(512) void k_scores(
    const float* __restrict__ hpre, const float* __restrict__ a_s,
    const float* __restrict__ a_d, float* __restrict__ ss, float* __restrict__ sd) {
  int n0 = blockIdx.x * 4;
  int t = threadIdx.x;
  float as_ = a_s[t], ad_ = a_d[t];
#pragma unroll
  for (int v = 0; v < 4; ++v) {
    float h = hpre[(size_t)(n0 + v) * 512 + t];
    float vs = h * as_;
    float vd = h * ad_;
#pragma unroll
    for (int o = 32; o > 0; o >>= 1) {
      vs += __shfl_xor(vs, o);
      vd += __shfl_xor(vd, o);
    }
    if ((t & 63) == 0) {
      ss[(size_t)(n0 + v) * 8 + (t >> 6)] = vs;
      sd[(size_t)(n0 + v) * 8 + (t >> 6)] = vd;
    }
  }
}

// ---------------------------------------------------------------------------
// GAT aggregation, one block per graph. Exploits the fixed topology:
// node j receives from all i (self-loop i==j has edge_attr = 0).
// Real edge (i->j) id within graph = i*4 + (j>i ? j-1 : j).
// In-place safe: all reads of hpre staged to LDS before any write.
// Output is relu(agg + b). POOL also emits the graph mean.
// ---------------------------------------------------------------------------
template <bool POOL>
__global__ __launch_bounds__(256) void k_agg(
    const float* __restrict__ hpre, const float* __restrict__ ss,
    const float* __restrict__ sd, const float* __restrict__ eattr,
    const float* __restrict__ We, const float* __restrict__ ae,
    const float* __restrict__ bvec, float* __restrict__ hout,
    float* __restrict__ gmean) {
  int g = blockIdx.x;
  int t = threadIdx.x;
  __shared__ float sh[5 * 512];
  __shared__ float sal[5][5][8];  // [dst j][src i][head]
  __shared__ float sss[5][8], ssd[5][8], sce[8];
  const float* hp = hpre + (size_t)g * 5 * 512;
  for (int i = t; i < 2560; i += 256) sh[i] = hp[i];
  if (t < 40) {
    sss[t >> 3][t & 7] = ss[(size_t)g * 40 + t];
    ssd[t >> 3][t & 7] = sd[(size_t)g * 40 + t];
  }
  if (t >= 64 && t < 72) {
    int h = t - 64;
    float c = 0.f;
#pragma unroll
    for (int k = 0; k < 64; ++k) c = fmaf(We[h * 64 + k], ae[h * 64 + k], c);
    sce[h] = c;
  }
  __syncthreads();
  if (t < 40) {
    int j = t >> 3, h = t & 7;
    float lg[5], m = -1e30f;
#pragma unroll
    for (int i = 0; i < 5; ++i) {
      float l = sss[i][h] + ssd[j][h];
      if (i != j) {
        int p = i * 4 + (j > i ? j - 1 : j);
        l = fmaf(eattr[(size_t)g * 20 + p], sce[h], l);
      }
      l = l > 0.f ? l : 0.2f * l;  // leaky_relu(0.2)
      lg[i] = l;
      m = fmaxf(m, l);
    }
    float s = 0.f;
#pragma unroll
    for (int i = 0; i < 5; ++i) {
      lg[i] = expf(lg[i] - m);
      s += lg[i];
    }
    float inv = 1.f / (s + 1e-16f);
#pragma unroll
    for (int i = 0; i < 5; ++i) sal[j][i][h] = lg[i] * inv;
  }
  __syncthreads();
  for (int d = t; d < 512; d += 256) {
    int h = d >> 6;
    float b = bvec[d];
    float gs = 0.f;
#pragma unroll
    for (int j = 0; j < 5; ++j) {
      float acc = b;
#pragma unroll
      for (int i = 0; i < 5; ++i) acc = fmaf(sal[j][i][h], sh[i * 512 + d], acc);
      acc = fmaxf(acc, 0.f);  // outer relu
      hout[((size_t)g * 5 + j) * 512 + d] = acc;
      gs += acc;
    }
    if (POOL) gmean[(size_t)g * 512 + d] = gs * 0.2f;
  }
}

// ---------------------------------------------------------------------------
// Tiled fp32 GEMM: C[M,N] = A[M,K] @ B[K,N] (+bias, +relu optional)
// BM=128 BN=64 BK=16, 256 threads, 8x4 microtile.
// Requires M%128==0, N%64==0, K%16==0.
// ---------------------------------------------------------------------------
template <bool BIAS, bool RELU>
__global__ __launch_bounds__(256) void gemm_f32(
    const float* __restrict__ A, const float* __restrict__ B,
    const float* __restrict__ bias, float* __restrict__ C, int M, int N, int K) {
  __shared__ float As[16][132];
  __shared__ float Bs[16][68];
  int t = threadIdx.x;
  int m0 = blockIdx.y * 128;
  int n0 = blockIdx.x * 64;
  int tc = t & 15;   // 4 cols each
  int tr = t >> 4;   // 8 rows each
  int lr = t >> 2;   // A load row (and +64)
  int lk = (t & 3) * 4;
  int br = t >> 4;         // B load k-row
  int bc = (t & 15) * 4;   // B load col
  float acc[8][4];
#pragma unroll
  for (int i = 0; i < 8; ++i)
#pragma unroll
    for (int j = 0; j < 4; ++j) acc[i][j] = 0.f;

  for (int k0 = 0; k0 < K; k0 += 16) {
    float4 a0 = *(const float4*)&A[(size_t)(m0 + lr) * K + k0 + lk];
    float4 a1 = *(const float4*)&A[(size_t)(m0 + lr + 64) * K + k0 + lk];
    float4 b0 = *(const float4*)&B[(size_t)(k0 + br) * N + n0 + bc];
    As[lk + 0][lr] = a0.x; As[lk + 1][lr] = a0.y;
    As[lk + 2][lr] = a0.z; As[lk + 3][lr] = a0.w;
    As[lk + 0][lr + 64] = a1.x; As[lk + 1][lr + 64] = a1.y;
    As[lk + 2][lr + 64] = a1.z; As[lk + 3][lr + 64] = a1.w;
    *(float4*)&Bs[br][bc] = b0;
    __syncthreads();
#pragma unroll
    for (int kk = 0; kk < 16; ++kk) {
      float4 av0 = *(const float4*)&As[kk][tr * 8];
      float4 av1 = *(const float4*)&As[kk][tr * 8 + 4];
      float4 bv = *(const float4*)&Bs[kk][tc * 4];
      float a[8] = {av0.x, av0.y, av0.z, av0.w, av1.x, av1.y, av1.z, av1.w};
      float b[4] = {bv.x, bv.y, bv.z, bv.w};
#pragma unroll
      for (int i = 0; i < 8; ++i)
#pragma unroll
        for (int j = 0; j < 4; ++j) acc[i][j] = fmaf(a[i], b[j], acc[i][j]);
    }
    __syncthreads();
  }
  float4 bb = make_float4(0.f, 0.f, 0.f, 0.f);
  if (BIAS) bb = *(const float4*)&bias[n0 + tc * 4];
#pragma unroll
  for (int i = 0; i < 8; ++i) {
    int m = m0 + tr * 8 + i;
    float4 v;
    v.x = acc[i][0] + bb.x;
    v.y = acc[i][1] + bb.y;
    v.z = acc[i][2] + bb.z;
    v.w = acc[i][3] + bb.w;
    if (RELU) {
      v.x = fmaxf(v.x, 0.f); v.y = fmaxf(v.y, 0.f);
      v.z = fmaxf(v.z, 0.f); v.w = fmaxf(v.w, 0.f);
    }
    *(float4*)&C[(size_t)m * N + n0 + tc * 4] = v;
  }
}

// ---------------------------------------------------------------------------
// Final per-graph heads: pi/q (4 each), term (1), actor mean/std (15 each).
// out row = [pi(4) | q(4) | term(1) | mean(15) | std(15)]  (39 floats)
// ---------------------------------------------------------------------------
__global__ __launch_bounds__(64) void k_out(
    const float* __restrict__ phid, const float* __restrict__ qhid,
    const float* __restrict__ thid, const float* __restrict__ gterm,
    const float* __restrict__ ahidraw, const float* __restrict__ pw2,
    const float* __restrict__ pb2, const float* __restrict__ qw2,
    const float* __restrict__ qb2, const float* __restrict__ tw2,
    const float* __restrict__ tb2, const float* __restrict__ aw2,
    const float* __restrict__ ab2, const float* __restrict__ alim,
    float* __restrict__ out) {
  int g = blockIdx.x;
  int t = threadIdx.x;
  __shared__ float ah[5][128];
  for (int i = t; i < 640; i += 64) {
    int a = i >> 7, j = i & 127;
    ah[a][j] = fmaxf(ahidraw[((size_t)g * 5 + a) * 128 + j] + gterm[(size_t)g * 128 + j], 0.f);
  }
  __syncthreads();
  float* orow = out + (size_t)g * 39;
  if (t < 4) {
    float acc = pb2[t];
    for (int j = 0; j < 128; ++j) acc = fmaf(phid[(size_t)g * 128 + j], pw2[j * 4 + t], acc);
    orow[t] = acc;
  } else if (t < 8) {
    int o = t - 4;
    float acc = qb2[o];
    for (int j = 0; j < 128; ++j) acc = fmaf(qhid[(size_t)g * 128 + j], qw2[j * 4 + o], acc);
    orow[t] = acc;
  } else if (t == 8) {
    float acc = tb2[0];
    for (int j = 0; j < 64; ++j) acc = fmaf(thid[(size_t)g * 64 + j], tw2[j], acc);
    orow[8] = 1.f / (1.f + expf(-acc));
  } else if (t >= 9 && t < 24) {
    int i = t - 9;
    int a = i / 3, c = i % 3;
    float acc = ab2[c];
    for (int j = 0; j < 128; ++j) acc = fmaf(ah[a][j], aw2[j * 6 + c], acc);
    orow[t] = tanhf(acc) * alim[c];
  } else if (t >= 24 && t < 39) {
    int i = t - 24;
    int a = i / 3, c = i % 3;
    float acc = ab2[3 + c];
    for (int j = 0; j < 128; ++j) acc = fmaf(ah[a][j], aw2[j * 6 + 3 + c], acc);
    orow[t] = 0.05f + (1.f / (1.f + expf(-acc))) * 0.45f + 1e-6f;
  }
}

// ---------------------------------------------------------------------------
extern "C" void kernel_launch(void* const* d_in, const int* in_sizes, int n_in,
                              void* d_out, int out_size, void* d_ws, size_t ws_size,
                              hipStream_t stream) {
  const float* x     = (const float*)d_in[0];
  const float* eattr = (const float*)d_in[1];
  // d_in[2..4]: edge_src/edge_dst/batch_map — topology is fixed, derived analytically
  const float* W1  = (const float*)d_in[5];
  const float* as1 = (const float*)d_in[6];
  const float* ad1 = (const float*)d_in[7];
  const float* We1 = (const float*)d_in[8];
  const float* ae1 = (const float*)d_in[9];
  const float* b1  = (const float*)d_in[10];
  const float* W2  = (const float*)d_in[11];
  const float* as2 = (const float*)d_in[12];
  const float* ad2 = (const float*)d_in[13];
  const float* We2 = (const float*)d_in[14];
  const float* ae2 = (const float*)d_in[15];
  const float* b2  = (const float*)d_in[16];
  const float* pw1 = (const float*)d_in[17];
  const float* pb1 = (const float*)d_in[18];
  const float* pw2 = (const float*)d_in[19];
  const float* pb2 = (const float*)d_in[20];
  const float* qw1 = (const float*)d_in[21];
  const float* qb1 = (const float*)d_in[22];
  const float* qw2 = (const float*)d_in[23];
  const float* qb2 = (const float*)d_in[24];
  const float* aw1 = (const float*)d_in[25];
  const float* ab1 = (const float*)d_in[26];
  const float* aw2 = (const float*)d_in[27];
  const float* ab2 = (const float*)d_in[28];
  const float* tw1 = (const float*)d_in[29];
  const float* tb1 = (const float*)d_in[30];
  const float* tw2 = (const float*)d_in[31];
  const float* tb2 = (const float*)d_in[32];
  const float* alim = (const float*)d_in[33];

  float* ws = (float*)d_ws;
  const size_t BIG = (size_t)NN * DD;  // 20,971,520 floats
  float* buf0  = ws;             // h1pre -> h1 (in-place agg); later head scratch
  float* buf1  = buf0 + BIG;     // h2pre -> h2 (in-place agg)
  float* ssb   = buf1 + BIG;     // N*8
  float* sdb   = ssb + (size_t)NN * 8;
  float* gmean = sdb + (size_t)NN * 8;          // G*512
  // head scratch aliases buf0 (h1 dead after the big GEMM)
  float* phid  = buf0;                          // G*128
  float* qhid  = phid + (size_t)GG * 128;
  float* thid  = qhid + (size_t)GG * 128;       // G*64
  float* gterm = thid + (size_t)GG * 64;        // G*128
  float* ahid  = gterm + (size_t)GG * 128;      // N*128

  // --- layer 1 ---
  k1_inproj<<<NN / 4, 512, 0, stream>>>(x, W1, as1, ad1, buf0, ssb, sdb);
  k_agg<false><<<GG, 256, 0, stream>>>(buf0, ssb, sdb, eattr, We1, ae1, b1, buf0, nullptr);
  // --- layer 2 ---
  gemm_f32<false, false><<<dim3(DD / 64, NN / 128), 256, 0, stream>>>(
      buf0, W2, nullptr, buf1, NN, DD, DD);
  k_scores<<<NN / 4, 512, 0, stream>>>(buf1, as2, ad2, ssb, sdb);
  k_agg<true><<<GG, 256, 0, stream>>>(buf1, ssb, sdb, eattr, We2, ae2, b2, buf1, gmean);
  // --- heads (hidden layers) ---
  gemm_f32<true, true><<<dim3(2, GG / 128), 256, 0, stream>>>(gmean, pw1, pb1, phid, GG, 128, DD);
  gemm_f32<true, true><<<dim3(2, GG / 128), 256, 0, stream>>>(gmean, qw1, qb1, qhid, GG, 128, DD);
  gemm_f32<true, true><<<dim3(1, GG / 128), 256, 0, stream>>>(gmean, tw1, tb1, thid, GG, 64, DD);
  gemm_f32<true, false><<<dim3(2, GG / 128), 256, 0, stream>>>(
      gmean, aw1 + (size_t)512 * 128, ab1, gterm, GG, 128, DD);
  gemm_f32<false, false><<<dim3(2, NN / 128), 256, 0, stream>>>(
      buf1, aw1, nullptr, ahid, NN, 128, DD);
  // --- heads (output layers) + assembly ---
  k_out<<<GG, 64, 0, stream>>>(phid, qhid, thid, gterm, ahid, pw2, pb2, qw2, qb2,
                               tw2, tb2, aw2, ab2, alim, (float*)d_out);
}

// Round 2
// 355.373 us; speedup vs baseline: 2.1799x; 2.1799x over previous
//
#include <hip/hip_runtime.h>
#include <hip/hip_bf16.h>
#include <math.h>

#define GG 8192
#define AA 5
#define NN (GG * AA)        // 40960
#define DD 512

typedef unsigned short ushort_t;
typedef unsigned int uint_t;

__device__ inline float bf2f(ushort_t u) {
  union { uint_t i; float f; } c; c.i = ((uint_t)u) << 16; return c.f;
}
__device__ inline ushort_t f2bf(float f) {
  union { float f; uint_t i; } c; c.f = f;
  uint_t r = c.i + 0x7fffu + ((c.i >> 16) & 1u);   // round-to-nearest-even
  return (ushort_t)(r >> 16);
}

using frag8 = __attribute__((ext_vector_type(8))) short;
using f32x4 = __attribute__((ext_vector_type(4))) float;

typedef __attribute__((address_space(3))) void lds_void;
typedef __attribute__((address_space(1))) const void gbl_void;
#define GLL(g, l) __builtin_amdgcn_global_load_lds((gbl_void*)(g), (lds_void*)(l), 16, 0, 0)

// ---------------------------------------------------------------------------
// shared alpha computation: 40 threads -> sal[dst j][src i][head]
// ---------------------------------------------------------------------------
__device__ inline void alpha40(int t, const float (&sss)[5][8], const float (&ssd)[5][8],
                               const float* sce, const float* seat, float (&sal)[5][5][8]) {
  if (t < 40) {
    int j = t >> 3, h = t & 7;
    float lg[5], m = -1e30f;
#pragma unroll
    for (int i = 0; i < 5; ++i) {
      float l = sss[i][h] + ssd[j][h];
      if (i != j) l = fmaf(seat[i * 4 + (j > i ? j - 1 : j)], sce[h], l);
      l = l > 0.f ? l : 0.2f * l;   // leaky_relu(0.2)
      lg[i] = l; m = fmaxf(m, l);
    }
    float s = 0.f;
#pragma unroll
    for (int i = 0; i < 5; ++i) { lg[i] = __expf(lg[i] - m); s += lg[i]; }
    float inv = 1.f / (s + 1e-16f);
#pragma unroll
    for (int i = 0; i < 5; ++i) sal[j][i][h] = lg[i] * inv;
  }
}

// ---------------------------------------------------------------------------
// Layer 1, fully fused: one graph per 512-thread block.
// x@W1 in regs -> scores (wave reduce; wave w == head w) -> alpha -> aggregate
// -> relu -> bf16 h1.
// ---------------------------------------------------------------------------
__global__ __launch_bounds__(512) void k_l1(
    const float* __restrict__ x, const float* __restrict__ eattr,
    const float* __restrict__ W1, const float* __restrict__ as1,
    const float* __restrict__ ad1, const float* __restrict__ We1,
    const float* __restrict__ ae1, const float* __restrict__ b1,
    ushort_t* __restrict__ h1) {
  int g = blockIdx.x;
  int t = threadIdx.x;
  int w = t >> 6, lane = t & 63;
  __shared__ float sx[5][32];
  __shared__ float sss[5][8], ssd[5][8], sce[8], seat[20];
  __shared__ float sal[5][5][8];
  if (t < 145) sx[t / 29][t % 29] = x[(size_t)g * 145 + t];
  if (t >= 160 && t < 180) seat[t - 160] = eattr[(size_t)g * 20 + (t - 160)];
  if (t >= 192 && t < 200) {
    int h = t - 192; float c = 0.f;
    for (int k = 0; k < 64; ++k) c = fmaf(We1[h * 64 + k], ae1[h * 64 + k], c);
    sce[h] = c;
  }
  __syncthreads();
  float acc[5] = {0.f, 0.f, 0.f, 0.f, 0.f};
  float a_s = as1[t], a_d = ad1[t];
#pragma unroll
  for (int k = 0; k < 29; ++k) {
    float wv = W1[k * 512 + t];
#pragma unroll
    for (int v = 0; v < 5; ++v) acc[v] = fmaf(sx[v][k], wv, acc[v]);
  }
#pragma unroll
  for (int v = 0; v < 5; ++v) {
    float vs = acc[v] * a_s, vd = acc[v] * a_d;
#pragma unroll
    for (int o = 32; o > 0; o >>= 1) { vs += __shfl_xor(vs, o); vd += __shfl_xor(vd, o); }
    if (lane == 0) { sss[v][w] = vs; ssd[v][w] = vd; }
  }
  __syncthreads();
  alpha40(t, sss, ssd, sce, seat, sal);
  __syncthreads();
  float b = b1[t];
#pragma unroll
  for (int j = 0; j < 5; ++j) {
    float o = b;
#pragma unroll
    for (int i = 0; i < 5; ++i) o = fmaf(sal[j][i][w], acc[i], o);
    h1[((size_t)g * 5 + j) * 512 + t] = f2bf(fmaxf(o, 0.f));
  }
}

// ---------------------------------------------------------------------------
// Layer 2 aggregation with fused score computation. Reads bf16 h2pre,
// writes bf16 h2 and bf16 gmean.
// ---------------------------------------------------------------------------
__global__ __launch_bounds__(512) void k_l2(
    const ushort_t* __restrict__ h2pre, const float* __restrict__ eattr,
    const float* __restrict__ as2, const float* __restrict__ ad2,
    const float* __restrict__ We2, const float* __restrict__ ae2,
    const float* __restrict__ b2, ushort_t* __restrict__ h2,
    ushort_t* __restrict__ gmean) {
  int g = blockIdx.x;
  int t = threadIdx.x;
  int w = t >> 6, lane = t & 63;
  __shared__ float sh[5][512];
  __shared__ float sss[5][8], ssd[5][8], sce[8], seat[20];
  __shared__ float sal[5][5][8];
  const uint_t* hp = (const uint_t*)(h2pre + (size_t)g * 2560);
#pragma unroll
  for (int i = t; i < 1280; i += 512) {
    uint_t u = hp[i];
    sh[0][2 * i]     = bf2f((ushort_t)(u & 0xffff));
    sh[0][2 * i + 1] = bf2f((ushort_t)(u >> 16));
  }
  if (t >= 512 - 32 && t < 512 - 12) seat[t - (512 - 32)] = eattr[(size_t)g * 20 + (t - (512 - 32))];
  if (t >= 512 - 8) {
    int h = t - (512 - 8); float c = 0.f;
    for (int k = 0; k < 64; ++k) c = fmaf(We2[h * 64 + k], ae2[h * 64 + k], c);
    sce[h] = c;
  }
  __syncthreads();
  float a_s = as2[t], a_d = ad2[t];
  float hv[5];
#pragma unroll
  for (int v = 0; v < 5; ++v) {
    hv[v] = sh[v][t];
    float vs = hv[v] * a_s, vd = hv[v] * a_d;
#pragma unroll
    for (int o = 32; o > 0; o >>= 1) { vs += __shfl_xor(vs, o); vd += __shfl_xor(vd, o); }
    if (lane == 0) { sss[v][w] = vs; ssd[v][w] = vd; }
  }
  __syncthreads();
  alpha40(t, sss, ssd, sce, seat, sal);
  __syncthreads();
  float b = b2[t];
  float gs = 0.f;
#pragma unroll
  for (int j = 0; j < 5; ++j) {
    float o = b;
#pragma unroll
    for (int i = 0; i < 5; ++i) o = fmaf(sal[j][i][w], hv[i], o);
    o = fmaxf(o, 0.f);
    h2[((size_t)g * 5 + j) * 512 + t] = f2bf(o);
    gs += o;
  }
  gmean[(size_t)g * 512 + t] = f2bf(gs * 0.2f);
}

// ---------------------------------------------------------------------------
// bf16 MFMA GEMM: C[M,N] = A[M,K] @ BT[N,K]^T. 128x128 tile, BK=64,
// 256 threads (4 waves, 2x2), 4x4 frags of 16x16x32, global_load_lds staging.
// EPI: 0 = bf16 out; 1 = f32 out; 2 = f32 out + bias + relu(col<320)
// ---------------------------------------------------------------------------
template <int EPI>
__global__ __launch_bounds__(256) void gemm_mfma(
    const ushort_t* __restrict__ A, const ushort_t* __restrict__ BT,
    const float* __restrict__ bias, void* __restrict__ Cv, int M, int N, int K) {
  __shared__ ushort_t As[128][64];
  __shared__ ushort_t Bs[128][64];
  int t = threadIdx.x;
  int lane = t & 63;
  int wv = t >> 6;
  int wr = (wv >> 1) * 64, wc = (wv & 1) * 64;
  int m0 = blockIdx.y * 128, n0 = blockIdx.x * 128;
  f32x4 acc[4][4] = {};
  int srow = t >> 3;
  int scol = (t & 7) * 8;
  char* asb = (char*)&As[0][0];
  char* bsb = (char*)&Bs[0][0];
  for (int k0 = 0; k0 < K; k0 += 64) {
#pragma unroll
    for (int r = 0; r < 4; ++r) {
      int row = r * 32 + srow;
      GLL(A + (size_t)(m0 + row) * K + k0 + scol, asb + r * 4096 + t * 16);
      GLL(BT + (size_t)(n0 + row) * K + k0 + scol, bsb + r * 4096 + t * 16);
    }
    __syncthreads();
#pragma unroll
    for (int kk = 0; kk < 64; kk += 32) {
      int ko = kk + (lane >> 4) * 8;
      frag8 af[4], bfr[4];
#pragma unroll
      for (int m = 0; m < 4; ++m) af[m] = *(const frag8*)&As[wr + m * 16 + (lane & 15)][ko];
#pragma unroll
      for (int n = 0; n < 4; ++n) bfr[n] = *(const frag8*)&Bs[wc + n * 16 + (lane & 15)][ko];
#pragma unroll
      for (int m = 0; m < 4; ++m)
#pragma unroll
        for (int n = 0; n < 4; ++n)
          acc[m][n] = __builtin_amdgcn_mfma_f32_16x16x32_bf16(af[m], bfr[n], acc[m][n], 0, 0, 0);
    }
    __syncthreads();
  }
  int r4 = (lane >> 4) * 4;
  int cl = lane & 15;
#pragma unroll
  for (int m = 0; m < 4; ++m) {
#pragma unroll
    for (int n = 0; n < 4; ++n) {
      int col = n0 + wc + n * 16 + cl;
      float bb = (EPI == 2) ? bias[col] : 0.f;
#pragma unroll
      for (int r = 0; r < 4; ++r) {
        int row = m0 + wr + m * 16 + r4 + r;
        float v = acc[m][n][r] + bb;
        if (EPI == 2 && col < 320) v = fmaxf(v, 0.f);
        if (EPI == 0) ((ushort_t*)Cv)[(size_t)row * N + col] = f2bf(v);
        else          ((float*)Cv)[(size_t)row * N + col] = v;
      }
    }
  }
}

// ---------------------------------------------------------------------------
// Prep: bf16-transpose W2; pack+transpose head weights [512 cols x 512 k]:
// [0,128)=pw1 [128,256)=qw1 [256,320)=tw1 [320,448)=aw1_bot [448,512)=0;
// aw1_top transposed; packed bias.
// ---------------------------------------------------------------------------
__global__ __launch_bounds__(256) void k_prep(
    const float* __restrict__ W2, const float* __restrict__ pw1,
    const float* __restrict__ qw1, const float* __restrict__ tw1,
    const float* __restrict__ aw1, const float* __restrict__ pb1,
    const float* __restrict__ qb1, const float* __restrict__ tb1,
    const float* __restrict__ ab1, ushort_t* __restrict__ W2T,
    ushort_t* __restrict__ WcatT, ushort_t* __restrict__ aw1topT,
    float* __restrict__ bcat) {
  int i = blockIdx.x * 256 + threadIdx.x;
  if (i >= 512 * 512) return;
  int n = i >> 9, k = i & 511;
  W2T[(size_t)n * 512 + k] = f2bf(W2[(size_t)k * 512 + n]);
  float v;
  if (n < 128)      v = pw1[(size_t)k * 128 + n];
  else if (n < 256) v = qw1[(size_t)k * 128 + (n - 128)];
  else if (n < 320) v = tw1[(size_t)k * 64 + (n - 256)];
  else if (n < 448) v = aw1[(size_t)(512 + k) * 128 + (n - 320)];
  else              v = 0.f;
  WcatT[(size_t)n * 512 + k] = f2bf(v);
  if (n < 128) aw1topT[(size_t)n * 512 + k] = f2bf(aw1[(size_t)k * 128 + n]);
  if (k == 0) {
    float bv;
    if (n < 128)      bv = pb1[n];
    else if (n < 256) bv = qb1[n - 128];
    else if (n < 320) bv = tb1[n - 256];
    else if (n < 448) bv = ab1[n - 320];
    else              bv = 0.f;
    bcat[n] = bv;
  }
}

// ---------------------------------------------------------------------------
// Final heads: 4 graphs per 256-thread block.
// out row = [pi(4) | q(4) | term(1) | mean(15) | std(15)]
// ---------------------------------------------------------------------------
__global__ __launch_bounds__(256) void k_out(
    const float* __restrict__ hcat, const float* __restrict__ ahid,
    const float* __restrict__ pw2, const float* __restrict__ pb2,
    const float* __restrict__ qw2, const float* __restrict__ qb2,
    const float* __restrict__ tw2, const float* __restrict__ tb2,
    const float* __restrict__ aw2, const float* __restrict__ ab2,
    const float* __restrict__ alim, float* __restrict__ out) {
  int gi = threadIdx.x >> 6;
  int g = blockIdx.x * 4 + gi;
  int t = threadIdx.x & 63;
  __shared__ float ah[4][5][128];
  const float* grow = hcat + (size_t)g * 512;
  const float* gterm = grow + 320;
  for (int i = t; i < 640; i += 64) {
    int a = i >> 7, j = i & 127;
    ah[gi][a][j] = fmaxf(ahid[((size_t)g * 5 + a) * 128 + j] + gterm[j], 0.f);
  }
  __syncthreads();
  float* orow = out + (size_t)g * 39;
  if (t < 4) {
    float acc = pb2[t];
    for (int j = 0; j < 128; ++j) acc = fmaf(grow[j], pw2[j * 4 + t], acc);
    orow[t] = acc;
  } else if (t < 8) {
    int o = t - 4;
    float acc = qb2[o];
    for (int j = 0; j < 128; ++j) acc = fmaf(grow[128 + j], qw2[j * 4 + o], acc);
    orow[t] = acc;
  } else if (t == 8) {
    float acc = tb2[0];
    for (int j = 0; j < 64; ++j) acc = fmaf(grow[256 + j], tw2[j], acc);
    orow[8] = 1.f / (1.f + expf(-acc));
  } else if (t >= 9 && t < 24) {
    int i = t - 9;
    int a = i / 3, c = i % 3;
    float acc = ab2[c];
    for (int j = 0; j < 128; ++j) acc = fmaf(ah[gi][a][j], aw2[j * 6 + c], acc);
    orow[t] = tanhf(acc) * alim[c];
  } else if (t >= 24 && t < 39) {
    int i = t - 24;
    int a = i / 3, c = i % 3;
    float acc = ab2[3 + c];
    for (int j = 0; j < 128; ++j) acc = fmaf(ah[gi][a][j], aw2[j * 6 + 3 + c], acc);
    orow[t] = 0.05f + (1.f / (1.f + expf(-acc))) * 0.45f + 1e-6f;
  }
}

// ---------------------------------------------------------------------------
extern "C" void kernel_launch(void* const* d_in, const int* in_sizes, int n_in,
                              void* d_out, int out_size, void* d_ws, size_t ws_size,
                              hipStream_t stream) {
  const float* x     = (const float*)d_in[0];
  const float* eattr = (const float*)d_in[1];
  const float* W1  = (const float*)d_in[5];
  const float* as1 = (const float*)d_in[6];
  const float* ad1 = (const float*)d_in[7];
  const float* We1 = (const float*)d_in[8];
  const float* ae1 = (const float*)d_in[9];
  const float* b1  = (const float*)d_in[10];
  const float* W2  = (const float*)d_in[11];
  const float* as2 = (const float*)d_in[12];
  const float* ad2 = (const float*)d_in[13];
  const float* We2 = (const float*)d_in[14];
  const float* ae2 = (const float*)d_in[15];
  const float* b2  = (const float*)d_in[16];
  const float* pw1 = (const float*)d_in[17];
  const float* pb1 = (const float*)d_in[18];
  const float* pw2 = (const float*)d_in[19];
  const float* pb2 = (const float*)d_in[20];
  const float* qw1 = (const float*)d_in[21];
  const float* qb1 = (const float*)d_in[22];
  const float* qw2 = (const float*)d_in[23];
  const float* qb2 = (const float*)d_in[24];
  const float* aw1 = (const float*)d_in[25];
  const float* ab1 = (const float*)d_in[26];
  const float* aw2 = (const float*)d_in[27];
  const float* ab2 = (const float*)d_in[28];
  const float* tw1 = (const float*)d_in[29];
  const float* tb1 = (const float*)d_in[30];
  const float* tw2 = (const float*)d_in[31];
  const float* tb2 = (const float*)d_in[32];
  const float* alim = (const float*)d_in[33];

  const size_t BIGE = (size_t)NN * DD;  // 20,971,520 elements
  char* base = (char*)d_ws;
  ushort_t* h1      = (ushort_t*)base;                       // 42MB
  ushort_t* h2pre   = h1 + BIGE;                             // 42MB
  ushort_t* h2      = h2pre + BIGE;                          // 42MB
  ushort_t* gmean   = h2 + BIGE;                             // 8MB
  ushort_t* W2T     = gmean + (size_t)GG * DD;               // 0.5MB
  ushort_t* WcatT   = W2T + (size_t)DD * DD;                 // 0.5MB
  ushort_t* aw1topT = WcatT + (size_t)DD * DD;               // 0.125MB
  float*    bcat    = (float*)(aw1topT + (size_t)128 * DD);  // 2KB
  float*    ahid    = (float*)(bcat + DD);                   // 21MB
  float*    hcat    = ahid + (size_t)NN * 128;               // 16MB

  k_prep<<<(512 * 512 + 255) / 256, 256, 0, stream>>>(
      W2, pw1, qw1, tw1, aw1, pb1, qb1, tb1, ab1, W2T, WcatT, aw1topT, bcat);
  k_l1<<<GG, 512, 0, stream>>>(x, eattr, W1, as1, ad1, We1, ae1, b1, h1);
  gemm_mfma<0><<<dim3(DD / 128, NN / 128), 256, 0, stream>>>(
      h1, W2T, nullptr, h2pre, NN, DD, DD);
  k_l2<<<GG, 512, 0, stream>>>(h2pre, eattr, as2, ad2, We2, ae2, b2, h2, gmean);
  gemm_mfma<1><<<dim3(1, NN / 128), 256, 0, stream>>>(
      h2, aw1topT, nullptr, ahid, NN, 128, DD);
  gemm_mfma<2><<<dim3(DD / 128, GG / 128), 256, 0, stream>>>(
      gmean, WcatT, bcat, hcat, GG, DD, DD);
  k_out<<<GG / 4, 256, 0, stream>>>(hcat, ahid, pw2, pb2, qw2, qb2,
                                    tw2, tb2, aw2, ab2, alim, (float*)d_out);
}

// Round 3
// 215.998 us; speedup vs baseline: 3.5865x; 1.6453x over previous
//
#include <hip/hip_runtime.h>
#include <hip/hip_bf16.h>
#include <math.h>

#define GG 8192
#define AA 5
#define NN (GG * AA)        // 40960
#define DD 512

typedef unsigned short ushort_t;
typedef unsigned int uint_t;

__device__ inline float bf2f(ushort_t u) {
  union { uint_t i; float f; } c; c.i = ((uint_t)u) << 16; return c.f;
}
__device__ inline ushort_t f2bf(float f) {
  union { float f; uint_t i; } c; c.f = f;
  uint_t r = c.i + 0x7fffu + ((c.i >> 16) & 1u);   // round-to-nearest-even
  return (ushort_t)(r >> 16);
}

using frag8 = __attribute__((ext_vector_type(8))) short;
using f32x4 = __attribute__((ext_vector_type(4))) float;

typedef __attribute__((address_space(3))) void lds_void;
typedef __attribute__((address_space(1))) const void gbl_void;
#define GLL(g, l) __builtin_amdgcn_global_load_lds((gbl_void*)(g), (lds_void*)(l), 16, 0, 0)

// ---------------------------------------------------------------------------
// Prep (grid = 1024 + 10240 blocks):
//  blocks [0,1024): bf16 weight transposes/packs + sce dots (once, not per graph)
//  blocks [1024,..): xpad = bf16(x) padded [40960, 64]
// ---------------------------------------------------------------------------
__global__ __launch_bounds__(256) void k_prep(
    const float* __restrict__ x, const float* __restrict__ W1,
    const float* __restrict__ W2, const float* __restrict__ pw1,
    const float* __restrict__ qw1, const float* __restrict__ tw1,
    const float* __restrict__ aw1, const float* __restrict__ pb1,
    const float* __restrict__ qb1, const float* __restrict__ tb1,
    const float* __restrict__ ab1, const float* __restrict__ We1,
    const float* __restrict__ ae1, const float* __restrict__ We2,
    const float* __restrict__ ae2, ushort_t* __restrict__ xpad,
    ushort_t* __restrict__ W1T, ushort_t* __restrict__ W2T,
    ushort_t* __restrict__ WcatT, ushort_t* __restrict__ aw1topT,
    float* __restrict__ bcat, float* __restrict__ sce) {
  int b = blockIdx.x;
  int t = threadIdx.x;
  if (b < 1024) {
    int i = b * 256 + t;            // 0 .. 262143
    int n = i >> 9, k = i & 511;
    W2T[(size_t)n * 512 + k] = f2bf(W2[(size_t)k * 512 + n]);
    float v;
    if (n < 128)      v = pw1[(size_t)k * 128 + n];
    else if (n < 256) v = qw1[(size_t)k * 128 + (n - 128)];
    else if (n < 320) v = tw1[(size_t)k * 64 + (n - 256)];
    else if (n < 448) v = aw1[(size_t)(512 + k) * 128 + (n - 320)];
    else              v = 0.f;
    WcatT[(size_t)n * 512 + k] = f2bf(v);
    if (n < 128) aw1topT[(size_t)n * 512 + k] = f2bf(aw1[(size_t)k * 128 + n]);
    if (k == 0) {
      float bv;
      if (n < 128)      bv = pb1[n];
      else if (n < 256) bv = qb1[n - 128];
      else if (n < 320) bv = tb1[n - 256];
      else if (n < 448) bv = ab1[n - 320];
      else              bv = 0.f;
      bcat[n] = bv;
    }
    if (i < 512 * 64) {
      int nn = i >> 6, kk = i & 63;
      W1T[i] = (kk < 29) ? f2bf(W1[(size_t)kk * 512 + nn]) : (ushort_t)0;
    }
    if (i < 16) {
      int h = i & 7;
      const float* Wp = (i < 8) ? We1 : We2;
      const float* ap = (i < 8) ? ae1 : ae2;
      float c = 0.f;
      for (int k2 = 0; k2 < 64; ++k2) c = fmaf(Wp[h * 64 + k2], ap[h * 64 + k2], c);
      sce[i] = c;
    }
  } else {
    int i = (b - 1024) * 256 + t;   // 0 .. 2621439
    int n = i >> 6, k = i & 63;
    xpad[i] = (k < 29) ? f2bf(x[(size_t)n * 29 + k]) : (ushort_t)0;
  }
}

// ---------------------------------------------------------------------------
// Scores: one thread per (node, head). ss = <h[n,h,:], a_s[h,:]>, same for sd.
// Coalesced 128B/thread row segments; a_s/a_d staged in LDS with 65-stride
// (h*64 would alias all heads to one bank).
// ---------------------------------------------------------------------------
__global__ __launch_bounds__(256) void k_score(
    const ushort_t* __restrict__ hpre, const float* __restrict__ a_s,
    const float* __restrict__ a_d, float* __restrict__ ss,
    float* __restrict__ sd) {
  __shared__ float sas[520], sad[520];
  int t = threadIdx.x;
#pragma unroll
  for (int i = t; i < 512; i += 256) {
    int li = (i >> 6) * 65 + (i & 63);
    sas[li] = a_s[i];
    sad[li] = a_d[i];
  }
  __syncthreads();
  int gt = blockIdx.x * 256 + t;     // n*8 + h
  int h = gt & 7;
  const uint4* p = (const uint4*)(hpre + ((size_t)(gt >> 3)) * 512 + h * 64);
  float vs = 0.f, vd = 0.f;
#pragma unroll
  for (int q = 0; q < 8; ++q) {
    uint4 u = p[q];
    uint_t ws[4] = {u.x, u.y, u.z, u.w};
#pragma unroll
    for (int e = 0; e < 4; ++e) {
      float h0 = bf2f((ushort_t)(ws[e] & 0xffff));
      float h1 = bf2f((ushort_t)(ws[e] >> 16));
      int c = h * 65 + q * 8 + e * 2;
      vs = fmaf(h0, sas[c], vs);     vd = fmaf(h0, sad[c], vd);
      vs = fmaf(h1, sas[c + 1], vs); vd = fmaf(h1, sad[c + 1], vd);
    }
  }
  ss[gt] = vs;
  sd[gt] = vd;
}

// ---------------------------------------------------------------------------
// GAT aggregation: 2 graphs per 256-thread block, in-place (stage->barrier->
// write). Alpha (80 threads) runs concurrently with LDS staging; sce is
// precomputed. POOL also emits graph mean (bf16).
// ---------------------------------------------------------------------------
template <bool POOL>
__global__ __launch_bounds__(256) void k_agg(
    ushort_t* __restrict__ h, const float* __restrict__ ss,
    const float* __restrict__ sd, const float* __restrict__ eattr,
    const float* __restrict__ sce, const float* __restrict__ bvec,
    ushort_t* __restrict__ gmean) {
  int g0 = blockIdx.x * 2;
  int t = threadIdx.x;
  __shared__ uint2 shs[1280];          // 2 graphs x 5 nodes x 512 bf16 (10 KB)
  __shared__ float sal[400];           // [gi][j][i][hd]
  const uint2* src = (const uint2*)(h + (size_t)g0 * 2560);
#pragma unroll
  for (int i = 0; i < 5; ++i) shs[i * 256 + t] = src[i * 256 + t];
  if (t < 80) {
    int gi = t / 40, jh = t % 40;
    int j = jh >> 3, hd = jh & 7;
    int g = g0 + gi;
    float sdj = sd[((size_t)g * 5 + j) * 8 + hd];
    float ce = sce[hd];
    float lg[5], m = -1e30f;
#pragma unroll
    for (int i = 0; i < 5; ++i) {
      float l = ss[((size_t)g * 5 + i) * 8 + hd] + sdj;
      if (i != j) l = fmaf(eattr[(size_t)g * 20 + i * 4 + (j > i ? j - 1 : j)], ce, l);
      l = l > 0.f ? l : 0.2f * l;      // leaky_relu(0.2)
      lg[i] = l; m = fmaxf(m, l);
    }
    float s = 0.f;
#pragma unroll
    for (int i = 0; i < 5; ++i) { lg[i] = __expf(lg[i] - m); s += lg[i]; }
    float inv = 1.f / (s + 1e-16f);
#pragma unroll
    for (int i = 0; i < 5; ++i) sal[gi * 200 + j * 40 + i * 8 + hd] = lg[i] * inv;
  }
  __syncthreads();
  int gi = t >> 7, cq = t & 127;       // 4 channels per thread
  int c0 = cq * 4, hd = cq >> 4;
  float4 bb = *(const float4*)&bvec[c0];
  float hv[5][4];
#pragma unroll
  for (int i = 0; i < 5; ++i) {
    uint2 u = shs[gi * 640 + i * 128 + cq];
    hv[i][0] = bf2f((ushort_t)(u.x & 0xffff));
    hv[i][1] = bf2f((ushort_t)(u.x >> 16));
    hv[i][2] = bf2f((ushort_t)(u.y & 0xffff));
    hv[i][3] = bf2f((ushort_t)(u.y >> 16));
  }
  uint2* dst = (uint2*)(h + (size_t)g0 * 2560);
  float gs[4] = {0.f, 0.f, 0.f, 0.f};
#pragma unroll
  for (int j = 0; j < 5; ++j) {
    float o0 = bb.x, o1 = bb.y, o2 = bb.z, o3 = bb.w;
#pragma unroll
    for (int i = 0; i < 5; ++i) {
      float a = sal[gi * 200 + j * 40 + i * 8 + hd];
      o0 = fmaf(a, hv[i][0], o0); o1 = fmaf(a, hv[i][1], o1);
      o2 = fmaf(a, hv[i][2], o2); o3 = fmaf(a, hv[i][3], o3);
    }
    o0 = fmaxf(o0, 0.f); o1 = fmaxf(o1, 0.f);
    o2 = fmaxf(o2, 0.f); o3 = fmaxf(o3, 0.f);
    uint2 w;
    w.x = (uint_t)f2bf(o0) | ((uint_t)f2bf(o1) << 16);
    w.y = (uint_t)f2bf(o2) | ((uint_t)f2bf(o3) << 16);
    dst[gi * 640 + j * 128 + cq] = w;
    if (POOL) { gs[0] += o0; gs[1] += o1; gs[2] += o2; gs[3] += o3; }
  }
  if (POOL) {
    uint2 w;
    w.x = (uint_t)f2bf(gs[0] * 0.2f) | ((uint_t)f2bf(gs[1] * 0.2f) << 16);
    w.y = (uint_t)f2bf(gs[2] * 0.2f) | ((uint_t)f2bf(gs[3] * 0.2f) << 16);
    ((uint2*)gmean)[(size_t)(g0 + gi) * 128 + cq] = w;
  }
}

// ---------------------------------------------------------------------------
// bf16 MFMA GEMM: C[M,N] = A[M,K] @ BT[N,K]^T. 128x128 tile, BK=64,
// 256 threads (4 waves, 2x2), 4x4 frags of 16x16x32, global_load_lds staging.
// EPI: 0 = bf16 out; 1 = f32 out; 2 = f32 out + bias + relu(col<320)
// ---------------------------------------------------------------------------
template <int EPI>
__global__ __launch_bounds__(256) void gemm_mfma(
    const ushort_t* __restrict__ A, const ushort_t* __restrict__ BT,
    const float* __restrict__ bias, void* __restrict__ Cv, int M, int N, int K) {
  __shared__ ushort_t As[128][64];
  __shared__ ushort_t Bs[128][64];
  int t = threadIdx.x;
  int lane = t & 63;
  int wv = t >> 6;
  int wr = (wv >> 1) * 64, wc = (wv & 1) * 64;
  int m0 = blockIdx.y * 128, n0 = blockIdx.x * 128;
  f32x4 acc[4][4] = {};
  int srow = t >> 3;
  int scol = (t & 7) * 8;
  char* asb = (char*)&As[0][0];
  char* bsb = (char*)&Bs[0][0];
  for (int k0 = 0; k0 < K; k0 += 64) {
#pragma unroll
    for (int r = 0; r < 4; ++r) {
      int row = r * 32 + srow;
      GLL(A + (size_t)(m0 + row) * K + k0 + scol, asb + r * 4096 + t * 16);
      GLL(BT + (size_t)(n0 + row) * K + k0 + scol, bsb + r * 4096 + t * 16);
    }
    __syncthreads();
#pragma unroll
    for (int kk = 0; kk < 64; kk += 32) {
      int ko = kk + (lane >> 4) * 8;
      frag8 af[4], bfr[4];
#pragma unroll
      for (int m = 0; m < 4; ++m) af[m] = *(const frag8*)&As[wr + m * 16 + (lane & 15)][ko];
#pragma unroll
      for (int n = 0; n < 4; ++n) bfr[n] = *(const frag8*)&Bs[wc + n * 16 + (lane & 15)][ko];
#pragma unroll
      for (int m = 0; m < 4; ++m)
#pragma unroll
        for (int n = 0; n < 4; ++n)
          acc[m][n] = __builtin_amdgcn_mfma_f32_16x16x32_bf16(af[m], bfr[n], acc[m][n], 0, 0, 0);
    }
    __syncthreads();
  }
  int r4 = (lane >> 4) * 4;
  int cl = lane & 15;
#pragma unroll
  for (int m = 0; m < 4; ++m) {
#pragma unroll
    for (int n = 0; n < 4; ++n) {
      int col = n0 + wc + n * 16 + cl;
      float bb = (EPI == 2) ? bias[col] : 0.f;
#pragma unroll
      for (int r = 0; r < 4; ++r) {
        int row = m0 + wr + m * 16 + r4 + r;
        float v = acc[m][n][r] + bb;
        if (EPI == 2 && col < 320) v = fmaxf(v, 0.f);
        if (EPI == 0) ((ushort_t*)Cv)[(size_t)row * N + col] = f2bf(v);
        else          ((float*)Cv)[(size_t)row * N + col] = v;
      }
    }
  }
}

// ---------------------------------------------------------------------------
// Final heads: 4 graphs per 256-thread block.
// out row = [pi(4) | q(4) | term(1) | mean(15) | std(15)]
// ---------------------------------------------------------------------------
__global__ __launch_bounds__(256) void k_out(
    const float* __restrict__ hcat, const float* __restrict__ ahid,
    const float* __restrict__ pw2, const float* __restrict__ pb2,
    const float* __restrict__ qw2, const float* __restrict__ qb2,
    const float* __restrict__ tw2, const float* __restrict__ tb2,
    const float* __restrict__ aw2, const float* __restrict__ ab2,
    const float* __restrict__ alim, float* __restrict__ out) {
  int gi = threadIdx.x >> 6;
  int g = blockIdx.x * 4 + gi;
  int t = threadIdx.x & 63;
  __shared__ float ah[4][5][128];
  const float* grow = hcat + (size_t)g * 512;
  const float* gterm = grow + 320;
  for (int i = t; i < 640; i += 64) {
    int a = i >> 7, j = i & 127;
    ah[gi][a][j] = fmaxf(ahid[((size_t)g * 5 + a) * 128 + j] + gterm[j], 0.f);
  }
  __syncthreads();
  float* orow = out + (size_t)g * 39;
  if (t < 4) {
    float acc = pb2[t];
    for (int j = 0; j < 128; ++j) acc = fmaf(grow[j], pw2[j * 4 + t], acc);
    orow[t] = acc;
  } else if (t < 8) {
    int o = t - 4;
    float acc = qb2[o];
    for (int j = 0; j < 128; ++j) acc = fmaf(grow[128 + j], qw2[j * 4 + o], acc);
    orow[t] = acc;
  } else if (t == 8) {
    float acc = tb2[0];
    for (int j = 0; j < 64; ++j) acc = fmaf(grow[256 + j], tw2[j], acc);
    orow[8] = 1.f / (1.f + expf(-acc));
  } else if (t >= 9 && t < 24) {
    int i = t - 9;
    int a = i / 3, c = i % 3;
    float acc = ab2[c];
    for (int j = 0; j < 128; ++j) acc = fmaf(ah[gi][a][j], aw2[j * 6 + c], acc);
    orow[t] = tanhf(acc) * alim[c];
  } else if (t >= 24 && t < 39) {
    int i = t - 24;
    int a = i / 3, c = i % 3;
    float acc = ab2[3 + c];
    for (int j = 0; j < 128; ++j) acc = fmaf(ah[gi][a][j], aw2[j * 6 + 3 + c], acc);
    orow[t] = 0.05f + (1.f / (1.f + expf(-acc))) * 0.45f + 1e-6f;
  }
}

// ---------------------------------------------------------------------------
extern "C" void kernel_launch(void* const* d_in, const int* in_sizes, int n_in,
                              void* d_out, int out_size, void* d_ws, size_t ws_size,
                              hipStream_t stream) {
  const float* x     = (const float*)d_in[0];
  const float* eattr = (const float*)d_in[1];
  const float* W1  = (const float*)d_in[5];
  const float* as1 = (const float*)d_in[6];
  const float* ad1 = (const float*)d_in[7];
  const float* We1 = (const float*)d_in[8];
  const float* ae1 = (const float*)d_in[9];
  const float* b1  = (const float*)d_in[10];
  const float* W2  = (const float*)d_in[11];
  const float* as2 = (const float*)d_in[12];
  const float* ad2 = (const float*)d_in[13];
  const float* We2 = (const float*)d_in[14];
  const float* ae2 = (const float*)d_in[15];
  const float* b2  = (const float*)d_in[16];
  const float* pw1 = (const float*)d_in[17];
  const float* pb1 = (const float*)d_in[18];
  const float* pw2 = (const float*)d_in[19];
  const float* pb2 = (const float*)d_in[20];
  const float* qw1 = (const float*)d_in[21];
  const float* qb1 = (const float*)d_in[22];
  const float* qw2 = (const float*)d_in[23];
  const float* qb2 = (const float*)d_in[24];
  const float* aw1 = (const float*)d_in[25];
  const float* ab1 = (const float*)d_in[26];
  const float* aw2 = (const float*)d_in[27];
  const float* ab2 = (const float*)d_in[28];
  const float* tw1 = (const float*)d_in[29];
  const float* tb1 = (const float*)d_in[30];
  const float* tw2 = (const float*)d_in[31];
  const float* tb2 = (const float*)d_in[32];
  const float* alim = (const float*)d_in[33];

  const size_t BIGE = (size_t)NN * DD;
  char* p = (char*)d_ws;
  ushort_t* h1    = (ushort_t*)p; p += BIGE * 2;                 // 42MB (h1pre -> h1)
  ushort_t* h2    = (ushort_t*)p; p += BIGE * 2;                 // 42MB (h2pre -> h2)
  ushort_t* gmean = (ushort_t*)p; p += (size_t)GG * DD * 2;      // 8.4MB
  ushort_t* xpad  = (ushort_t*)p; p += (size_t)NN * 64 * 2;      // 5.2MB
  ushort_t* W1T   = (ushort_t*)p; p += (size_t)512 * 64 * 2;
  ushort_t* W2T   = (ushort_t*)p; p += (size_t)512 * 512 * 2;
  ushort_t* WcatT = (ushort_t*)p; p += (size_t)512 * 512 * 2;
  ushort_t* aw1topT = (ushort_t*)p; p += (size_t)128 * 512 * 2;
  float* bcat  = (float*)p; p += 512 * 4;
  float* sce   = (float*)p; p += 16 * 4;                          // [0,8)=L1 [8,16)=L2
  float* ssb   = (float*)p; p += (size_t)NN * 8 * 4;
  float* sdb   = (float*)p; p += (size_t)NN * 8 * 4;
  float* ahid  = (float*)p; p += (size_t)NN * 128 * 4;            // 21MB
  float* hcat  = (float*)p;                                       // 16.8MB

  k_prep<<<1024 + 10240, 256, 0, stream>>>(
      x, W1, W2, pw1, qw1, tw1, aw1, pb1, qb1, tb1, ab1,
      We1, ae1, We2, ae2, xpad, W1T, W2T, WcatT, aw1topT, bcat, sce);
  // --- layer 1 ---
  gemm_mfma<0><<<dim3(DD / 128, NN / 128), 256, 0, stream>>>(
      xpad, W1T, nullptr, h1, NN, DD, 64);
  k_score<<<NN * 8 / 256, 256, 0, stream>>>(h1, as1, ad1, ssb, sdb);
  k_agg<false><<<GG / 2, 256, 0, stream>>>(h1, ssb, sdb, eattr, sce, b1, nullptr);
  // --- layer 2 ---
  gemm_mfma<0><<<dim3(DD / 128, NN / 128), 256, 0, stream>>>(
      h1, W2T, nullptr, h2, NN, DD, DD);
  k_score<<<NN * 8 / 256, 256, 0, stream>>>(h2, as2, ad2, ssb, sdb);
  k_agg<true><<<GG / 2, 256, 0, stream>>>(h2, ssb, sdb, eattr, sce + 8, b2, gmean);
  // --- heads ---
  gemm_mfma<1><<<dim3(1, NN / 128), 256, 0, stream>>>(
      h2, aw1topT, nullptr, ahid, NN, 128, DD);
  gemm_mfma<2><<<dim3(DD / 128, GG / 128), 256, 0, stream>>>(
      gmean, WcatT, bcat, hcat, GG, DD, DD);
  k_out<<<GG / 4, 256, 0, stream>>>(hcat, ahid, pw2, pb2, qw2, qb2,
                                    tw2, tb2, aw2, ab2, alim, (float*)d_out);
}

// Round 4
// 193.838 us; speedup vs baseline: 3.9966x; 1.1143x over previous
//
#include <hip/hip_runtime.h>
#include <hip/hip_bf16.h>
#include <math.h>

#define GG 8192
#define AA 5
#define NN (GG * AA)        // 40960
#define DD 512

typedef unsigned short ushort_t;
typedef unsigned int uint_t;

__device__ inline float bf2f(ushort_t u) {
  union { uint_t i; float f; } c; c.i = ((uint_t)u) << 16; return c.f;
}
__device__ inline ushort_t f2bf(float f) {
  union { float f; uint_t i; } c; c.f = f;
  uint_t r = c.i + 0x7fffu + ((c.i >> 16) & 1u);   // round-to-nearest-even
  return (ushort_t)(r >> 16);
}

using frag8 = __attribute__((ext_vector_type(8))) short;
using f32x4 = __attribute__((ext_vector_type(4))) float;

typedef __attribute__((address_space(3))) void lds_void;
typedef __attribute__((address_space(1))) const void gbl_void;
#define GLL(g, l) __builtin_amdgcn_global_load_lds((gbl_void*)(g), (lds_void*)(l), 16, 0, 0)

// ---------------------------------------------------------------------------
// Prep (grid = 1024 + 10240 blocks):
//  blocks [0,1024): weight transposes/packs, sce dots, head-2 weight pack
//  blocks [1024,..): xpad = bf16(x) padded [40960, 64]
// ---------------------------------------------------------------------------
__global__ __launch_bounds__(256) void k_prep(
    const float* __restrict__ x, const float* __restrict__ W1,
    const float* __restrict__ W2, const float* __restrict__ pw1,
    const float* __restrict__ qw1, const float* __restrict__ tw1,
    const float* __restrict__ aw1, const float* __restrict__ pb1,
    const float* __restrict__ qb1, const float* __restrict__ tb1,
    const float* __restrict__ ab1, const float* __restrict__ We1,
    const float* __restrict__ ae1, const float* __restrict__ We2,
    const float* __restrict__ ae2, const float* __restrict__ pw2,
    const float* __restrict__ pb2, const float* __restrict__ qw2,
    const float* __restrict__ qb2, const float* __restrict__ tw2,
    const float* __restrict__ tb2, const float* __restrict__ aw2,
    const float* __restrict__ ab2, ushort_t* __restrict__ xpad,
    ushort_t* __restrict__ W1T, ushort_t* __restrict__ W2T,
    ushort_t* __restrict__ WcatT, ushort_t* __restrict__ aw1topT,
    float* __restrict__ bcat, float* __restrict__ sce,
    float* __restrict__ woutT, float* __restrict__ bout) {
  int b = blockIdx.x;
  int t = threadIdx.x;
  if (b < 1024) {
    int i = b * 256 + t;            // 0 .. 262143
    int n = i >> 9, k = i & 511;
    W2T[(size_t)n * 512 + k] = f2bf(W2[(size_t)k * 512 + n]);
    float v;
    if (n < 128)      v = pw1[(size_t)k * 128 + n];
    else if (n < 256) v = qw1[(size_t)k * 128 + (n - 128)];
    else if (n < 320) v = tw1[(size_t)k * 64 + (n - 256)];
    else if (n < 448) v = aw1[(size_t)(512 + k) * 128 + (n - 320)];
    else              v = 0.f;
    WcatT[(size_t)n * 512 + k] = f2bf(v);
    if (n < 128) aw1topT[(size_t)n * 512 + k] = f2bf(aw1[(size_t)k * 128 + n]);
    if (k == 0) {
      float bv;
      if (n < 128)      bv = pb1[n];
      else if (n < 256) bv = qb1[n - 128];
      else if (n < 320) bv = tb1[n - 256];
      else if (n < 448) bv = ab1[n - 320];
      else              bv = 0.f;
      bcat[n] = bv;
    }
    if (i < 512 * 64) {
      int nn = i >> 6, kk = i & 63;
      W1T[i] = (kk < 29) ? f2bf(W1[(size_t)kk * 512 + nn]) : (ushort_t)0;
    }
    if (i < 16) {
      int h = i & 7;
      const float* Wp = (i < 8) ? We1 : We2;
      const float* ap = (i < 8) ? ae1 : ae2;
      float c = 0.f;
      for (int k2 = 0; k2 < 64; ++k2) c = fmaf(Wp[h * 64 + k2], ap[h * 64 + k2], c);
      sce[i] = c;
    }
    // head-2 packed weights: woutT[j*40 + o], j in [0,128), o in [0,40)
    if (i < 5120) {
      int j = i / 40, o = i % 40;
      float wv;
      if (o < 4)       wv = pw2[j * 4 + o];
      else if (o < 8)  wv = qw2[j * 4 + (o - 4)];
      else if (o == 8) wv = (j < 64) ? tw2[j] : 0.f;
      else if (o < 24) wv = aw2[j * 6 + (o - 9) % 3];
      else if (o < 39) wv = aw2[j * 6 + 3 + (o - 24) % 3];
      else             wv = 0.f;
      woutT[i] = wv;
      if (j == 0) {
        float bv;
        if (o < 4)       bv = pb2[o];
        else if (o < 8)  bv = qb2[o - 4];
        else if (o == 8) bv = tb2[0];
        else if (o < 24) bv = ab2[(o - 9) % 3];
        else if (o < 39) bv = ab2[3 + (o - 24) % 3];
        else             bv = 0.f;
        bout[o] = bv;
      }
    }
  } else {
    int i = (b - 1024) * 256 + t;   // 0 .. 2621439
    int n = i >> 6, k = i & 63;
    xpad[i] = (k < 29) ? f2bf(x[(size_t)n * 29 + k]) : (ushort_t)0;
  }
}

// ---------------------------------------------------------------------------
// GAT aggregation with FUSED scores: 2 graphs per 256-thread block, in-place.
// Phase A: stage rows to LDS; 160 threads compute the (node,head) s/d dots
// from global (L1-hot). Phase B: 80 threads -> alpha. Phase C: aggregate.
// ---------------------------------------------------------------------------
template <bool POOL>
__global__ __launch_bounds__(256) void k_agg(
    ushort_t* __restrict__ h, const float* __restrict__ a_s,
    const float* __restrict__ a_d, const float* __restrict__ eattr,
    const float* __restrict__ sce, const float* __restrict__ bvec,
    ushort_t* __restrict__ gmean) {
  int g0 = blockIdx.x * 2;
  int t = threadIdx.x;
  __shared__ uint2 shs[1280];          // 2 graphs x 5 nodes x 512 bf16 (10 KB)
  __shared__ float sal[400];           // [gi][j][i][hd]
  __shared__ float sss[2][5][8], ssd[2][5][8];
  const uint2* src = (const uint2*)(h + (size_t)g0 * 2560);
#pragma unroll
  for (int i = 0; i < 5; ++i) shs[i * 256 + t] = src[i * 256 + t];
  if (t < 160) {
    int gi = t / 80, rem = t % 80;
    int nh = rem >> 1, which = rem & 1;
    int node = nh >> 3, hd = nh & 7;
    const float* av = (which ? a_d : a_s) + hd * 64;
    const uint2* p = src + gi * 640 + node * 128 + hd * 16;
    float c0 = 0.f, c1 = 0.f, c2 = 0.f, c3 = 0.f;
#pragma unroll
    for (int e = 0; e < 16; ++e) {
      uint2 u = p[e];
      c0 = fmaf(bf2f((ushort_t)(u.x & 0xffff)), av[e * 4 + 0], c0);
      c1 = fmaf(bf2f((ushort_t)(u.x >> 16)),    av[e * 4 + 1], c1);
      c2 = fmaf(bf2f((ushort_t)(u.y & 0xffff)), av[e * 4 + 2], c2);
      c3 = fmaf(bf2f((ushort_t)(u.y >> 16)),    av[e * 4 + 3], c3);
    }
    float tot = (c0 + c1) + (c2 + c3);
    if (which) ssd[gi][node][hd] = tot; else sss[gi][node][hd] = tot;
  }
  __syncthreads();
  if (t < 80) {
    int gi = t / 40, jh = t % 40;
    int j = jh >> 3, hd = jh & 7;
    int g = g0 + gi;
    float sdj = ssd[gi][j][hd];
    float ce = sce[hd];
    float lg[5], m = -1e30f;
#pragma unroll
    for (int i = 0; i < 5; ++i) {
      float l = sss[gi][i][hd] + sdj;
      if (i != j) l = fmaf(eattr[(size_t)g * 20 + i * 4 + (j > i ? j - 1 : j)], ce, l);
      l = l > 0.f ? l : 0.2f * l;      // leaky_relu(0.2)
      lg[i] = l; m = fmaxf(m, l);
    }
    float s = 0.f;
#pragma unroll
    for (int i = 0; i < 5; ++i) { lg[i] = __expf(lg[i] - m); s += lg[i]; }
    float inv = 1.f / (s + 1e-16f);
#pragma unroll
    for (int i = 0; i < 5; ++i) sal[gi * 200 + j * 40 + i * 8 + hd] = lg[i] * inv;
  }
  __syncthreads();
  int gi = t >> 7, cq = t & 127;       // 4 channels per thread
  int c0 = cq * 4, hd = cq >> 4;
  float4 bb = *(const float4*)&bvec[c0];
  float hv[5][4];
#pragma unroll
  for (int i = 0; i < 5; ++i) {
    uint2 u = shs[gi * 640 + i * 128 + cq];
    hv[i][0] = bf2f((ushort_t)(u.x & 0xffff));
    hv[i][1] = bf2f((ushort_t)(u.x >> 16));
    hv[i][2] = bf2f((ushort_t)(u.y & 0xffff));
    hv[i][3] = bf2f((ushort_t)(u.y >> 16));
  }
  uint2* dst = (uint2*)(h + (size_t)g0 * 2560);
  float gs[4] = {0.f, 0.f, 0.f, 0.f};
#pragma unroll
  for (int j = 0; j < 5; ++j) {
    float o0 = bb.x, o1 = bb.y, o2 = bb.z, o3 = bb.w;
#pragma unroll
    for (int i = 0; i < 5; ++i) {
      float a = sal[gi * 200 + j * 40 + i * 8 + hd];
      o0 = fmaf(a, hv[i][0], o0); o1 = fmaf(a, hv[i][1], o1);
      o2 = fmaf(a, hv[i][2], o2); o3 = fmaf(a, hv[i][3], o3);
    }
    o0 = fmaxf(o0, 0.f); o1 = fmaxf(o1, 0.f);
    o2 = fmaxf(o2, 0.f); o3 = fmaxf(o3, 0.f);
    uint2 w;
    w.x = (uint_t)f2bf(o0) | ((uint_t)f2bf(o1) << 16);
    w.y = (uint_t)f2bf(o2) | ((uint_t)f2bf(o3) << 16);
    dst[gi * 640 + j * 128 + cq] = w;
    if (POOL) { gs[0] += o0; gs[1] += o1; gs[2] += o2; gs[3] += o3; }
  }
  if (POOL) {
    uint2 w;
    w.x = (uint_t)f2bf(gs[0] * 0.2f) | ((uint_t)f2bf(gs[1] * 0.2f) << 16);
    w.y = (uint_t)f2bf(gs[2] * 0.2f) | ((uint_t)f2bf(gs[3] * 0.2f) << 16);
    ((uint2*)gmean)[(size_t)(g0 + gi) * 128 + cq] = w;
  }
}

// ---------------------------------------------------------------------------
// bf16 MFMA GEMM: C[M,N] = A[M,K] @ BT[N,K]^T. 128x128 tile, BK=64,
// 256 threads (4 waves, 2x2), 4x4 frags of 16x16x32, global_load_lds staging.
// EPI: 0 = bf16 out; 1 = f32 out; 2 = f32 out + bias + relu(col<320)
// ---------------------------------------------------------------------------
template <int EPI>
__global__ __launch_bounds__(256) void gemm_mfma(
    const ushort_t* __restrict__ A, const ushort_t* __restrict__ BT,
    const float* __restrict__ bias, void* __restrict__ Cv, int M, int N, int K) {
  __shared__ ushort_t As[128][64];
  __shared__ ushort_t Bs[128][64];
  int t = threadIdx.x;
  int lane = t & 63;
  int wv = t >> 6;
  int wr = (wv >> 1) * 64, wc = (wv & 1) * 64;
  int m0 = blockIdx.y * 128, n0 = blockIdx.x * 128;
  f32x4 acc[4][4] = {};
  int srow = t >> 3;
  int scol = (t & 7) * 8;
  char* asb = (char*)&As[0][0];
  char* bsb = (char*)&Bs[0][0];
  for (int k0 = 0; k0 < K; k0 += 64) {
#pragma unroll
    for (int r = 0; r < 4; ++r) {
      int row = r * 32 + srow;
      GLL(A + (size_t)(m0 + row) * K + k0 + scol, asb + r * 4096 + t * 16);
      GLL(BT + (size_t)(n0 + row) * K + k0 + scol, bsb + r * 4096 + t * 16);
    }
    __syncthreads();
#pragma unroll
    for (int kk = 0; kk < 64; kk += 32) {
      int ko = kk + (lane >> 4) * 8;
      frag8 af[4], bfr[4];
#pragma unroll
      for (int m = 0; m < 4; ++m) af[m] = *(const frag8*)&As[wr + m * 16 + (lane & 15)][ko];
#pragma unroll
      for (int n = 0; n < 4; ++n) bfr[n] = *(const frag8*)&Bs[wc + n * 16 + (lane & 15)][ko];
#pragma unroll
      for (int m = 0; m < 4; ++m)
#pragma unroll
        for (int n = 0; n < 4; ++n)
          acc[m][n] = __builtin_amdgcn_mfma_f32_16x16x32_bf16(af[m], bfr[n], acc[m][n], 0, 0, 0);
    }
    __syncthreads();
  }
  int r4 = (lane >> 4) * 4;
  int cl = lane & 15;
#pragma unroll
  for (int m = 0; m < 4; ++m) {
#pragma unroll
    for (int n = 0; n < 4; ++n) {
      int col = n0 + wc + n * 16 + cl;
      float bb = (EPI == 2) ? bias[col] : 0.f;
#pragma unroll
      for (int r = 0; r < 4; ++r) {
        int row = m0 + wr + m * 16 + r4 + r;
        float v = acc[m][n][r] + bb;
        if (EPI == 2 && col < 320) v = fmaxf(v, 0.f);
        if (EPI == 0) ((ushort_t*)Cv)[(size_t)row * N + col] = f2bf(v);
        else          ((float*)Cv)[(size_t)row * N + col] = v;
      }
    }
  }
}

// ---------------------------------------------------------------------------
// Final heads, uniform-work version: 4 graphs per 256-thread block, 64 lanes
// per graph, lane o computes output o (o>=40 duplicates o=39, no store).
// Inputs staged per-graph in LDS at +132-staggered segment offsets
// (conflict-free: distinct-bank broadcast groups). Weights woutT[j*40+o]
// coalesced. 4 accumulators -> dep chain 32.
// out row = [pi(4) | q(4) | term(1) | mean(15) | std(15)]
// ---------------------------------------------------------------------------
__global__ __launch_bounds__(256) void k_heads(
    const float* __restrict__ hcat, const float* __restrict__ ahid,
    const float* __restrict__ woutT, const float* __restrict__ bout,
    const float* __restrict__ alim, float* __restrict__ out) {
  int g0 = blockIdx.x * 4;
  int t = threadIdx.x;
  __shared__ float sbuf[4224];         // 4 graphs x 1056
  for (int i = t; i < 4224; i += 256) {
    int gi = i / 1056, r = i - gi * 1056;
    const float* grow = hcat + (size_t)(g0 + gi) * 512;
    float v = 0.f;
    if (r < 128)                  v = grow[r];
    else if (r >= 132 && r < 260) v = grow[128 + r - 132];
    else if (r >= 264 && r < 328) v = grow[256 + r - 264];
    else if (r >= 396) {
      int q = r - 396; int a = q / 132; int j = q - a * 132;
      if (j < 128)
        v = fmaxf(ahid[((size_t)(g0 + gi) * 5 + a) * 128 + j] + grow[320 + j], 0.f);
    }
    sbuf[i] = v;
  }
  __syncthreads();
  int gi = t >> 6, o = t & 63;
  int oc = o < 39 ? o : 39;
  int seg;
  if (oc < 4)       seg = 0;
  else if (oc < 8)  seg = 132;
  else if (oc == 8) seg = 264;
  else {
    int idx = (oc < 24) ? oc - 9 : oc - 24;
    seg = 396 + (idx / 3) * 132;
  }
  const float* ip = &sbuf[gi * 1056 + seg];
  float a0 = 0.f, a1 = 0.f, a2 = 0.f, a3 = 0.f;
#pragma unroll
  for (int j = 0; j < 128; j += 4) {
    a0 = fmaf(ip[j + 0], woutT[(j + 0) * 40 + oc], a0);
    a1 = fmaf(ip[j + 1], woutT[(j + 1) * 40 + oc], a1);
    a2 = fmaf(ip[j + 2], woutT[(j + 2) * 40 + oc], a2);
    a3 = fmaf(ip[j + 3], woutT[(j + 3) * 40 + oc], a3);
  }
  float res = (a0 + a1) + (a2 + a3) + bout[oc];
  if (o < 39) {
    if (o == 8)       res = 1.f / (1.f + __expf(-res));
    else if (o >= 24) res = 0.05f + 0.45f / (1.f + __expf(-res)) + 1e-6f;
    else if (o >= 9)  res = tanhf(res) * alim[(o - 9) % 3];
    out[(size_t)(g0 + gi) * 39 + o] = res;
  }
}

// ---------------------------------------------------------------------------
extern "C" void kernel_launch(void* const* d_in, const int* in_sizes, int n_in,
                              void* d_out, int out_size, void* d_ws, size_t ws_size,
                              hipStream_t stream) {
  const float* x     = (const float*)d_in[0];
  const float* eattr = (const float*)d_in[1];
  const float* W1  = (const float*)d_in[5];
  const float* as1 = (const float*)d_in[6];
  const float* ad1 = (const float*)d_in[7];
  const float* We1 = (const float*)d_in[8];
  const float* ae1 = (const float*)d_in[9];
  const float* b1  = (const float*)d_in[10];
  const float* W2  = (const float*)d_in[11];
  const float* as2 = (const float*)d_in[12];
  const float* ad2 = (const float*)d_in[13];
  const float* We2 = (const float*)d_in[14];
  const float* ae2 = (const float*)d_in[15];
  const float* b2  = (const float*)d_in[16];
  const float* pw1 = (const float*)d_in[17];
  const float* pb1 = (const float*)d_in[18];
  const float* pw2 = (const float*)d_in[19];
  const float* pb2 = (const float*)d_in[20];
  const float* qw1 = (const float*)d_in[21];
  const float* qb1 = (const float*)d_in[22];
  const float* qw2 = (const float*)d_in[23];
  const float* qb2 = (const float*)d_in[24];
  const float* aw1 = (const float*)d_in[25];
  const float* ab1 = (const float*)d_in[26];
  const float* aw2 = (const float*)d_in[27];
  const float* ab2 = (const float*)d_in[28];
  const float* tw1 = (const float*)d_in[29];
  const float* tb1 = (const float*)d_in[30];
  const float* tw2 = (const float*)d_in[31];
  const float* tb2 = (const float*)d_in[32];
  const float* alim = (const float*)d_in[33];

  const size_t BIGE = (size_t)NN * DD;
  char* p = (char*)d_ws;
  ushort_t* h1    = (ushort_t*)p; p += BIGE * 2;                 // 42MB (h1pre -> h1)
  ushort_t* h2    = (ushort_t*)p; p += BIGE * 2;                 // 42MB (h2pre -> h2)
  ushort_t* gmean = (ushort_t*)p; p += (size_t)GG * DD * 2;      // 8.4MB
  ushort_t* xpad  = (ushort_t*)p; p += (size_t)NN * 64 * 2;      // 5.2MB
  ushort_t* W1T   = (ushort_t*)p; p += (size_t)512 * 64 * 2;
  ushort_t* W2T   = (ushort_t*)p; p += (size_t)512 * 512 * 2;
  ushort_t* WcatT = (ushort_t*)p; p += (size_t)512 * 512 * 2;
  ushort_t* aw1topT = (ushort_t*)p; p += (size_t)128 * 512 * 2;
  float* bcat  = (float*)p; p += 512 * 4;
  float* sce   = (float*)p; p += 16 * 4;                          // [0,8)=L1 [8,16)=L2
  float* woutT = (float*)p; p += 5120 * 4;
  float* bout  = (float*)p; p += 40 * 4;
  float* ahid  = (float*)p; p += (size_t)NN * 128 * 4;            // 21MB
  float* hcat  = (float*)p;                                       // 16.8MB

  k_prep<<<1024 + 10240, 256, 0, stream>>>(
      x, W1, W2, pw1, qw1, tw1, aw1, pb1, qb1, tb1, ab1,
      We1, ae1, We2, ae2, pw2, pb2, qw2, qb2, tw2, tb2, aw2, ab2,
      xpad, W1T, W2T, WcatT, aw1topT, bcat, sce, woutT, bout);
  // --- layer 1 ---
  gemm_mfma<0><<<dim3(DD / 128, NN / 128), 256, 0, stream>>>(
      xpad, W1T, nullptr, h1, NN, DD, 64);
  k_agg<false><<<GG / 2, 256, 0, stream>>>(h1, as1, ad1, eattr, sce, b1, nullptr);
  // --- layer 2 ---
  gemm_mfma<0><<<dim3(DD / 128, NN / 128), 256, 0, stream>>>(
      h1, W2T, nullptr, h2, NN, DD, DD);
  k_agg<true><<<GG / 2, 256, 0, stream>>>(h2, as2, ad2, eattr, sce + 8, b2, gmean);
  // --- heads ---
  gemm_mfma<1><<<dim3(1, NN / 128), 256, 0, stream>>>(
      h2, aw1topT, nullptr, ahid, NN, 128, DD);
  gemm_mfma<2><<<dim3(DD / 128, GG / 128), 256, 0, stream>>>(
      gmean, WcatT, bcat, hcat, GG, DD, DD);
  k_heads<<<GG / 4, 256, 0, stream>>>(hcat, ahid, woutT, bout, alim, (float*)d_out);
}

// Round 5
// 180.400 us; speedup vs baseline: 4.2943x; 1.0745x over previous
//
#include <hip/hip_runtime.h>
#include <hip/hip_bf16.h>
#include <math.h>

#define GG 8192
#define AA 5
#define NN (GG * AA)        // 40960
#define DD 512

typedef unsigned short ushort_t;
typedef unsigned int uint_t;

__device__ inline float bf2f(ushort_t u) {
  union { uint_t i; float f; } c; c.i = ((uint_t)u) << 16; return c.f;
}
__device__ inline ushort_t f2bf(float f) {
  union { float f; uint_t i; } c; c.f = f;
  uint_t r = c.i + 0x7fffu + ((c.i >> 16) & 1u);   // round-to-nearest-even
  return (ushort_t)(r >> 16);
}

using frag8 = __attribute__((ext_vector_type(8))) short;
using f32x4 = __attribute__((ext_vector_type(4))) float;

typedef __attribute__((address_space(3))) void lds_void;
typedef __attribute__((address_space(1))) const void gbl_void;
#define GLL(g, l) __builtin_amdgcn_global_load_lds((gbl_void*)(g), (lds_void*)(l), 16, 0, 0)

// XCD-chunked bijective swizzle (requires nwg % 8 == 0): hw block b -> XCD b%8;
// give each XCD a contiguous logical range so n-blocks of one m-panel share L2.
__device__ inline int xcd_swz(int bid, int nwg) {
  return (bid & 7) * (nwg >> 3) + (bid >> 3);
}

// ---------------------------------------------------------------------------
// Prep (grid = 1024 + 10240 blocks):
//  blocks [0,1024): weight transposes/packs, sce dots, head-2 weight pack
//  blocks [1024,..): xpad = bf16(x) padded [40960, 64]
// ---------------------------------------------------------------------------
__global__ __launch_bounds__(256) void k_prep(
    const float* __restrict__ x, const float* __restrict__ W1,
    const float* __restrict__ W2, const float* __restrict__ pw1,
    const float* __restrict__ qw1, const float* __restrict__ tw1,
    const float* __restrict__ aw1, const float* __restrict__ pb1,
    const float* __restrict__ qb1, const float* __restrict__ tb1,
    const float* __restrict__ ab1, const float* __restrict__ We1,
    const float* __restrict__ ae1, const float* __restrict__ We2,
    const float* __restrict__ ae2, const float* __restrict__ pw2,
    const float* __restrict__ pb2, const float* __restrict__ qw2,
    const float* __restrict__ qb2, const float* __restrict__ tw2,
    const float* __restrict__ tb2, const float* __restrict__ aw2,
    const float* __restrict__ ab2, ushort_t* __restrict__ xpad,
    ushort_t* __restrict__ W1T, ushort_t* __restrict__ W2T,
    ushort_t* __restrict__ WcatT, ushort_t* __restrict__ aw1topT,
    float* __restrict__ bcat, float* __restrict__ sce,
    float* __restrict__ woutT, float* __restrict__ bout) {
  int b = blockIdx.x;
  int t = threadIdx.x;
  if (b < 1024) {
    int i = b * 256 + t;            // 0 .. 262143
    int n = i >> 9, k = i & 511;
    W2T[(size_t)n * 512 + k] = f2bf(W2[(size_t)k * 512 + n]);
    float v;
    if (n < 128)      v = pw1[(size_t)k * 128 + n];
    else if (n < 256) v = qw1[(size_t)k * 128 + (n - 128)];
    else if (n < 320) v = tw1[(size_t)k * 64 + (n - 256)];
    else if (n < 448) v = aw1[(size_t)(512 + k) * 128 + (n - 320)];
    else              v = 0.f;
    WcatT[(size_t)n * 512 + k] = f2bf(v);
    if (n < 128) aw1topT[(size_t)n * 512 + k] = f2bf(aw1[(size_t)k * 128 + n]);
    if (k == 0) {
      float bv;
      if (n < 128)      bv = pb1[n];
      else if (n < 256) bv = qb1[n - 128];
      else if (n < 320) bv = tb1[n - 256];
      else if (n < 448) bv = ab1[n - 320];
      else              bv = 0.f;
      bcat[n] = bv;
    }
    if (i < 512 * 64) {
      int nn = i >> 6, kk = i & 63;
      W1T[i] = (kk < 29) ? f2bf(W1[(size_t)kk * 512 + nn]) : (ushort_t)0;
    }
    if (i < 16) {
      int h = i & 7;
      const float* Wp = (i < 8) ? We1 : We2;
      const float* ap = (i < 8) ? ae1 : ae2;
      float c = 0.f;
      for (int k2 = 0; k2 < 64; ++k2) c = fmaf(Wp[h * 64 + k2], ap[h * 64 + k2], c);
      sce[i] = c;
    }
    // head-2 packed weights: woutT[j*40 + o], j in [0,128), o in [0,40)
    if (i < 5120) {
      int j = i / 40, o = i % 40;
      float wv;
      if (o < 4)       wv = pw2[j * 4 + o];
      else if (o < 8)  wv = qw2[j * 4 + (o - 4)];
      else if (o == 8) wv = (j < 64) ? tw2[j] : 0.f;
      else if (o < 24) wv = aw2[j * 6 + (o - 9) % 3];
      else if (o < 39) wv = aw2[j * 6 + 3 + (o - 24) % 3];
      else             wv = 0.f;
      woutT[i] = wv;
      if (j == 0) {
        float bv;
        if (o < 4)       bv = pb2[o];
        else if (o < 8)  bv = qb2[o - 4];
        else if (o == 8) bv = tb2[0];
        else if (o < 24) bv = ab2[(o - 9) % 3];
        else if (o < 39) bv = ab2[3 + (o - 24) % 3];
        else             bv = 0.f;
        bout[o] = bv;
      }
    }
  } else {
    int i = (b - 1024) * 256 + t;   // 0 .. 2621439
    int n = i >> 6, k = i & 63;
    xpad[i] = (k < 29) ? f2bf(x[(size_t)n * 29 + k]) : (ushort_t)0;
  }
}

// ---------------------------------------------------------------------------
// GAT aggregation with FUSED scores: 2 graphs per 256-thread block, in-place.
// ---------------------------------------------------------------------------
template <bool POOL>
__global__ __launch_bounds__(256) void k_agg(
    ushort_t* __restrict__ h, const float* __restrict__ a_s,
    const float* __restrict__ a_d, const float* __restrict__ eattr,
    const float* __restrict__ sce, const float* __restrict__ bvec,
    ushort_t* __restrict__ gmean) {
  int g0 = blockIdx.x * 2;
  int t = threadIdx.x;
  __shared__ uint2 shs[1280];          // 2 graphs x 5 nodes x 512 bf16 (10 KB)
  __shared__ float sal[400];           // [gi][j][i][hd]
  __shared__ float sss[2][5][8], ssd[2][5][8];
  const uint2* src = (const uint2*)(h + (size_t)g0 * 2560);
#pragma unroll
  for (int i = 0; i < 5; ++i) shs[i * 256 + t] = src[i * 256 + t];
  if (t < 160) {
    int gi = t / 80, rem = t % 80;
    int nh = rem >> 1, which = rem & 1;
    int node = nh >> 3, hd = nh & 7;
    const float* av = (which ? a_d : a_s) + hd * 64;
    const uint2* p = src + gi * 640 + node * 128 + hd * 16;
    float c0 = 0.f, c1 = 0.f, c2 = 0.f, c3 = 0.f;
#pragma unroll
    for (int e = 0; e < 16; ++e) {
      uint2 u = p[e];
      c0 = fmaf(bf2f((ushort_t)(u.x & 0xffff)), av[e * 4 + 0], c0);
      c1 = fmaf(bf2f((ushort_t)(u.x >> 16)),    av[e * 4 + 1], c1);
      c2 = fmaf(bf2f((ushort_t)(u.y & 0xffff)), av[e * 4 + 2], c2);
      c3 = fmaf(bf2f((ushort_t)(u.y >> 16)),    av[e * 4 + 3], c3);
    }
    float tot = (c0 + c1) + (c2 + c3);
    if (which) ssd[gi][node][hd] = tot; else sss[gi][node][hd] = tot;
  }
  __syncthreads();
  if (t < 80) {
    int gi = t / 40, jh = t % 40;
    int j = jh >> 3, hd = jh & 7;
    int g = g0 + gi;
    float sdj = ssd[gi][j][hd];
    float ce = sce[hd];
    float lg[5], m = -1e30f;
#pragma unroll
    for (int i = 0; i < 5; ++i) {
      float l = sss[gi][i][hd] + sdj;
      if (i != j) l = fmaf(eattr[(size_t)g * 20 + i * 4 + (j > i ? j - 1 : j)], ce, l);
      l = l > 0.f ? l : 0.2f * l;      // leaky_relu(0.2)
      lg[i] = l; m = fmaxf(m, l);
    }
    float s = 0.f;
#pragma unroll
    for (int i = 0; i < 5; ++i) { lg[i] = __expf(lg[i] - m); s += lg[i]; }
    float inv = 1.f / (s + 1e-16f);
#pragma unroll
    for (int i = 0; i < 5; ++i) sal[gi * 200 + j * 40 + i * 8 + hd] = lg[i] * inv;
  }
  __syncthreads();
  int gi = t >> 7, cq = t & 127;       // 4 channels per thread
  int c0 = cq * 4, hd = cq >> 4;
  float4 bb = *(const float4*)&bvec[c0];
  float hv[5][4];
#pragma unroll
  for (int i = 0; i < 5; ++i) {
    uint2 u = shs[gi * 640 + i * 128 + cq];
    hv[i][0] = bf2f((ushort_t)(u.x & 0xffff));
    hv[i][1] = bf2f((ushort_t)(u.x >> 16));
    hv[i][2] = bf2f((ushort_t)(u.y & 0xffff));
    hv[i][3] = bf2f((ushort_t)(u.y >> 16));
  }
  uint2* dst = (uint2*)(h + (size_t)g0 * 2560);
  float gs[4] = {0.f, 0.f, 0.f, 0.f};
#pragma unroll
  for (int j = 0; j < 5; ++j) {
    float o0 = bb.x, o1 = bb.y, o2 = bb.z, o3 = bb.w;
#pragma unroll
    for (int i = 0; i < 5; ++i) {
      float a = sal[gi * 200 + j * 40 + i * 8 + hd];
      o0 = fmaf(a, hv[i][0], o0); o1 = fmaf(a, hv[i][1], o1);
      o2 = fmaf(a, hv[i][2], o2); o3 = fmaf(a, hv[i][3], o3);
    }
    o0 = fmaxf(o0, 0.f); o1 = fmaxf(o1, 0.f);
    o2 = fmaxf(o2, 0.f); o3 = fmaxf(o3, 0.f);
    uint2 w;
    w.x = (uint_t)f2bf(o0) | ((uint_t)f2bf(o1) << 16);
    w.y = (uint_t)f2bf(o2) | ((uint_t)f2bf(o3) << 16);
    dst[gi * 640 + j * 128 + cq] = w;
    if (POOL) { gs[0] += o0; gs[1] += o1; gs[2] += o2; gs[3] += o3; }
  }
  if (POOL) {
    uint2 w;
    w.x = (uint_t)f2bf(gs[0] * 0.2f) | ((uint_t)f2bf(gs[1] * 0.2f) << 16);
    w.y = (uint_t)f2bf(gs[2] * 0.2f) | ((uint_t)f2bf(gs[3] * 0.2f) << 16);
    ((uint2*)gmean)[(size_t)(g0 + gi) * 128 + cq] = w;
  }
}

// ---------------------------------------------------------------------------
// bf16 MFMA GEMM, 2-phase double-buffered: C[M,N] = A[M,K] @ BT[N,K]^T.
// 128x128 tile, BK=32, LDS 2x(8KB A + 8KB B) = 32 KB, 256 threads (4 waves,
// 2x2), 4x4 frags of 16x16x32. Stage(next) issued BEFORE compute(cur); one
// barrier per K-step -> HBM latency hides under ds_read+MFMA (T3-minimum).
// 1-D grid with XCD-chunked swizzle (grid % 8 == 0).
// EPI: 0 = bf16 out; 1 = f32 out; 2 = f32 out + bias + relu(col<320)
// ---------------------------------------------------------------------------
template <int EPI>
__global__ __launch_bounds__(256) void gemm_mfma(
    const ushort_t* __restrict__ A, const ushort_t* __restrict__ BT,
    const float* __restrict__ bias, void* __restrict__ Cv,
    int M, int N, int K, int nxblk) {
  __shared__ ushort_t As[2][128][32];
  __shared__ ushort_t Bs[2][128][32];
  int t = threadIdx.x;
  int lane = t & 63;
  int wv = t >> 6;
  int wr = (wv >> 1) * 64, wc = (wv & 1) * 64;
  int lid = xcd_swz(blockIdx.x, gridDim.x);
  int m0 = (lid / nxblk) * 128, n0 = (lid % nxblk) * 128;
  f32x4 acc[4][4] = {};
  char* asb = (char*)&As[0][0][0];
  char* bsb = (char*)&Bs[0][0][0];
  // stage one K-tile (8 KB each of A,B): 512 chunks of 16B; 2 per thread
  int ch0 = t, ch1 = 256 + t;
  int row0 = ch0 >> 2, c0e = (ch0 & 3) * 8;   // elements
  int row1 = ch1 >> 2, c1e = (ch1 & 3) * 8;
  const int nt = K >> 5;
#define STAGE_TILE(bsel, kk0)                                                  \
  {                                                                            \
    GLL(A + (size_t)(m0 + row0) * K + (kk0) + c0e, asb + (bsel)*8192 + ch0*16);\
    GLL(A + (size_t)(m0 + row1) * K + (kk0) + c1e, asb + (bsel)*8192 + ch1*16);\
    GLL(BT + (size_t)(n0 + row0) * K + (kk0) + c0e, bsb + (bsel)*8192 + ch0*16);\
    GLL(BT + (size_t)(n0 + row1) * K + (kk0) + c1e, bsb + (bsel)*8192 + ch1*16);\
  }
  STAGE_TILE(0, 0);
  __syncthreads();
  for (int ts = 0; ts < nt; ++ts) {
    int cur = ts & 1;
    if (ts + 1 < nt) STAGE_TILE(cur ^ 1, (ts + 1) * 32);
    int ko = (lane >> 4) * 8;
    frag8 af[4], bfr[4];
#pragma unroll
    for (int m = 0; m < 4; ++m) af[m] = *(const frag8*)&As[cur][wr + m * 16 + (lane & 15)][ko];
#pragma unroll
    for (int n = 0; n < 4; ++n) bfr[n] = *(const frag8*)&Bs[cur][wc + n * 16 + (lane & 15)][ko];
#pragma unroll
    for (int m = 0; m < 4; ++m)
#pragma unroll
      for (int n = 0; n < 4; ++n)
        acc[m][n] = __builtin_amdgcn_mfma_f32_16x16x32_bf16(af[m], bfr[n], acc[m][n], 0, 0, 0);
    __syncthreads();
  }
#undef STAGE_TILE
  int r4 = (lane >> 4) * 4;
  int cl = lane & 15;
#pragma unroll
  for (int m = 0; m < 4; ++m) {
#pragma unroll
    for (int n = 0; n < 4; ++n) {
      int col = n0 + wc + n * 16 + cl;
      float bb = (EPI == 2) ? bias[col] : 0.f;
#pragma unroll
      for (int r = 0; r < 4; ++r) {
        int row = m0 + wr + m * 16 + r4 + r;
        float v = acc[m][n][r] + bb;
        if (EPI == 2 && col < 320) v = fmaxf(v, 0.f);
        if (EPI == 0) ((ushort_t*)Cv)[(size_t)row * N + col] = f2bf(v);
        else          ((float*)Cv)[(size_t)row * N + col] = v;
      }
    }
  }
}

// ---------------------------------------------------------------------------
// Final heads, uniform-work version (see round-4 notes).
// out row = [pi(4) | q(4) | term(1) | mean(15) | std(15)]
// ---------------------------------------------------------------------------
__global__ __launch_bounds__(256) void k_heads(
    const float* __restrict__ hcat, const float* __restrict__ ahid,
    const float* __restrict__ woutT, const float* __restrict__ bout,
    const float* __restrict__ alim, float* __restrict__ out) {
  int g0 = blockIdx.x * 4;
  int t = threadIdx.x;
  __shared__ float sbuf[4224];         // 4 graphs x 1056
  for (int i = t; i < 4224; i += 256) {
    int gi = i / 1056, r = i - gi * 1056;
    const float* grow = hcat + (size_t)(g0 + gi) * 512;
    float v = 0.f;
    if (r < 128)                  v = grow[r];
    else if (r >= 132 && r < 260) v = grow[128 + r - 132];
    else if (r >= 264 && r < 328) v = grow[256 + r - 264];
    else if (r >= 396) {
      int q = r - 396; int a = q / 132; int j = q - a * 132;
      if (j < 128)
        v = fmaxf(ahid[((size_t)(g0 + gi) * 5 + a) * 128 + j] + grow[320 + j], 0.f);
    }
    sbuf[i] = v;
  }
  __syncthreads();
  int gi = t >> 6, o = t & 63;
  int oc = o < 39 ? o : 39;
  int seg;
  if (oc < 4)       seg = 0;
  else if (oc < 8)  seg = 132;
  else if (oc == 8) seg = 264;
  else {
    int idx = (oc < 24) ? oc - 9 : oc - 24;
    seg = 396 + (idx / 3) * 132;
  }
  const float* ip = &sbuf[gi * 1056 + seg];
  float a0 = 0.f, a1 = 0.f, a2 = 0.f, a3 = 0.f;
#pragma unroll
  for (int j = 0; j < 128; j += 4) {
    a0 = fmaf(ip[j + 0], woutT[(j + 0) * 40 + oc], a0);
    a1 = fmaf(ip[j + 1], woutT[(j + 1) * 40 + oc], a1);
    a2 = fmaf(ip[j + 2], woutT[(j + 2) * 40 + oc], a2);
    a3 = fmaf(ip[j + 3], woutT[(j + 3) * 40 + oc], a3);
  }
  float res = (a0 + a1) + (a2 + a3) + bout[oc];
  if (o < 39) {
    if (o == 8)       res = 1.f / (1.f + __expf(-res));
    else if (o >= 24) res = 0.05f + 0.45f / (1.f + __expf(-res)) + 1e-6f;
    else if (o >= 9)  res = tanhf(res) * alim[(o - 9) % 3];
    out[(size_t)(g0 + gi) * 39 + o] = res;
  }
}

// ---------------------------------------------------------------------------
extern "C" void kernel_launch(void* const* d_in, const int* in_sizes, int n_in,
                              void* d_out, int out_size, void* d_ws, size_t ws_size,
                              hipStream_t stream) {
  const float* x     = (const float*)d_in[0];
  const float* eattr = (const float*)d_in[1];
  const float* W1  = (const float*)d_in[5];
  const float* as1 = (const float*)d_in[6];
  const float* ad1 = (const float*)d_in[7];
  const float* We1 = (const float*)d_in[8];
  const float* ae1 = (const float*)d_in[9];
  const float* b1  = (const float*)d_in[10];
  const float* W2  = (const float*)d_in[11];
  const float* as2 = (const float*)d_in[12];
  const float* ad2 = (const float*)d_in[13];
  const float* We2 = (const float*)d_in[14];
  const float* ae2 = (const float*)d_in[15];
  const float* b2  = (const float*)d_in[16];
  const float* pw1 = (const float*)d_in[17];
  const float* pb1 = (const float*)d_in[18];
  const float* pw2 = (const float*)d_in[19];
  const float* pb2 = (const float*)d_in[20];
  const float* qw1 = (const float*)d_in[21];
  const float* qb1 = (const float*)d_in[22];
  const float* qw2 = (const float*)d_in[23];
  const float* qb2 = (const float*)d_in[24];
  const float* aw1 = (const float*)d_in[25];
  const float* ab1 = (const float*)d_in[26];
  const float* aw2 = (const float*)d_in[27];
  const float* ab2 = (const float*)d_in[28];
  const float* tw1 = (const float*)d_in[29];
  const float* tb1 = (const float*)d_in[30];
  const float* tw2 = (const float*)d_in[31];
  const float* tb2 = (const float*)d_in[32];
  const float* alim = (const float*)d_in[33];

  const size_t BIGE = (size_t)NN * DD;
  char* p = (char*)d_ws;
  ushort_t* h1    = (ushort_t*)p; p += BIGE * 2;                 // 42MB (h1pre -> h1)
  ushort_t* h2    = (ushort_t*)p; p += BIGE * 2;                 // 42MB (h2pre -> h2)
  ushort_t* gmean = (ushort_t*)p; p += (size_t)GG * DD * 2;      // 8.4MB
  ushort_t* xpad  = (ushort_t*)p; p += (size_t)NN * 64 * 2;      // 5.2MB
  ushort_t* W1T   = (ushort_t*)p; p += (size_t)512 * 64 * 2;
  ushort_t* W2T   = (ushort_t*)p; p += (size_t)512 * 512 * 2;
  ushort_t* WcatT = (ushort_t*)p; p += (size_t)512 * 512 * 2;
  ushort_t* aw1topT = (ushort_t*)p; p += (size_t)128 * 512 * 2;
  float* bcat  = (float*)p; p += 512 * 4;
  float* sce   = (float*)p; p += 16 * 4;                          // [0,8)=L1 [8,16)=L2
  float* woutT = (float*)p; p += 5120 * 4;
  float* bout  = (float*)p; p += 40 * 4;
  float* ahid  = (float*)p; p += (size_t)NN * 128 * 4;            // 21MB
  float* hcat  = (float*)p;                                       // 16.8MB

  k_prep<<<1024 + 10240, 256, 0, stream>>>(
      x, W1, W2, pw1, qw1, tw1, aw1, pb1, qb1, tb1, ab1,
      We1, ae1, We2, ae2, pw2, pb2, qw2, qb2, tw2, tb2, aw2, ab2,
      xpad, W1T, W2T, WcatT, aw1topT, bcat, sce, woutT, bout);
  // --- layer 1 ---
  gemm_mfma<0><<<(NN / 128) * (DD / 128), 256, 0, stream>>>(
      xpad, W1T, nullptr, h1, NN, DD, 64, DD / 128);
  k_agg<false><<<GG / 2, 256, 0, stream>>>(h1, as1, ad1, eattr, sce, b1, nullptr);
  // --- layer 2 ---
  gemm_mfma<0><<<(NN / 128) * (DD / 128), 256, 0, stream>>>(
      h1, W2T, nullptr, h2, NN, DD, DD, DD / 128);
  k_agg<true><<<GG / 2, 256, 0, stream>>>(h2, as2, ad2, eattr, sce + 8, b2, gmean);
  // --- heads ---
  gemm_mfma<1><<<(NN / 128) * 1, 256, 0, stream>>>(
      h2, aw1topT, nullptr, ahid, NN, 128, DD, 1);
  gemm_mfma<2><<<(GG / 128) * (DD / 128), 256, 0, stream>>>(
      gmean, WcatT, bcat, hcat, GG, DD, DD, DD / 128);
  k_heads<<<GG / 4, 256, 0, stream>>>(hcat, ahid, woutT, bout, alim, (float*)d_out);
}

// Round 6
// 164.874 us; speedup vs baseline: 4.6986x; 1.0942x over previous
//
#include <hip/hip_runtime.h>
#include <hip/hip_bf16.h>
#include <math.h>

#define GG 8192
#define AA 5
#define NN (GG * AA)        // 40960
#define DD 512

typedef unsigned short ushort_t;
typedef unsigned int uint_t;

__device__ inline float bf2f(ushort_t u) {
  union { uint_t i; float f; } c; c.i = ((uint_t)u) << 16; return c.f;
}
__device__ inline ushort_t f2bf(float f) {
  union { float f; uint_t i; } c; c.f = f;
  uint_t r = c.i + 0x7fffu + ((c.i >> 16) & 1u);   // round-to-nearest-even
  return (ushort_t)(r >> 16);
}

using frag8 = __attribute__((ext_vector_type(8))) short;
using f32x4 = __attribute__((ext_vector_type(4))) float;

typedef __attribute__((address_space(3))) void lds_void;
typedef __attribute__((address_space(1))) const void gbl_void;
#define GLL(g, l) __builtin_amdgcn_global_load_lds((gbl_void*)(g), (lds_void*)(l), 16, 0, 0)

// XCD-chunked bijective swizzle (requires nwg % 8 == 0).
__device__ inline int xcd_swz(int bid, int nwg) {
  return (bid & 7) * (nwg >> 3) + (bid >> 3);
}

// ---------------------------------------------------------------------------
// Prep (grid = 1024 + 10240 blocks) — unchanged from round 5.
// ---------------------------------------------------------------------------
__global__ __launch_bounds__(256) void k_prep(
    const float* __restrict__ x, const float* __restrict__ W1,
    const float* __restrict__ W2, const float* __restrict__ pw1,
    const float* __restrict__ qw1, const float* __restrict__ tw1,
    const float* __restrict__ aw1, const float* __restrict__ pb1,
    const float* __restrict__ qb1, const float* __restrict__ tb1,
    const float* __restrict__ ab1, const float* __restrict__ We1,
    const float* __restrict__ ae1, const float* __restrict__ We2,
    const float* __restrict__ ae2, const float* __restrict__ pw2,
    const float* __restrict__ pb2, const float* __restrict__ qw2,
    const float* __restrict__ qb2, const float* __restrict__ tw2,
    const float* __restrict__ tb2, const float* __restrict__ aw2,
    const float* __restrict__ ab2, ushort_t* __restrict__ xpad,
    ushort_t* __restrict__ W1T, ushort_t* __restrict__ W2T,
    ushort_t* __restrict__ WcatT, ushort_t* __restrict__ aw1topT,
    float* __restrict__ bcat, float* __restrict__ sce,
    float* __restrict__ woutT, float* __restrict__ bout) {
  int b = blockIdx.x;
  int t = threadIdx.x;
  if (b < 1024) {
    int i = b * 256 + t;            // 0 .. 262143
    int n = i >> 9, k = i & 511;
    W2T[(size_t)n * 512 + k] = f2bf(W2[(size_t)k * 512 + n]);
    float v;
    if (n < 128)      v = pw1[(size_t)k * 128 + n];
    else if (n < 256) v = qw1[(size_t)k * 128 + (n - 128)];
    else if (n < 320) v = tw1[(size_t)k * 64 + (n - 256)];
    else if (n < 448) v = aw1[(size_t)(512 + k) * 128 + (n - 320)];
    else              v = 0.f;
    WcatT[(size_t)n * 512 + k] = f2bf(v);
    if (n < 128) aw1topT[(size_t)n * 512 + k] = f2bf(aw1[(size_t)k * 128 + n]);
    if (k == 0) {
      float bv;
      if (n < 128)      bv = pb1[n];
      else if (n < 256) bv = qb1[n - 128];
      else if (n < 320) bv = tb1[n - 256];
      else if (n < 448) bv = ab1[n - 320];
      else              bv = 0.f;
      bcat[n] = bv;
    }
    if (i < 512 * 64) {
      int nn = i >> 6, kk = i & 63;
      W1T[i] = (kk < 29) ? f2bf(W1[(size_t)kk * 512 + nn]) : (ushort_t)0;
    }
    if (i < 16) {
      int h = i & 7;
      const float* Wp = (i < 8) ? We1 : We2;
      const float* ap = (i < 8) ? ae1 : ae2;
      float c = 0.f;
      for (int k2 = 0; k2 < 64; ++k2) c = fmaf(Wp[h * 64 + k2], ap[h * 64 + k2], c);
      sce[i] = c;
    }
    if (i < 5120) {
      int j = i / 40, o = i % 40;
      float wv;
      if (o < 4)       wv = pw2[j * 4 + o];
      else if (o < 8)  wv = qw2[j * 4 + (o - 4)];
      else if (o == 8) wv = (j < 64) ? tw2[j] : 0.f;
      else if (o < 24) wv = aw2[j * 6 + (o - 9) % 3];
      else if (o < 39) wv = aw2[j * 6 + 3 + (o - 24) % 3];
      else             wv = 0.f;
      woutT[i] = wv;
      if (j == 0) {
        float bv;
        if (o < 4)       bv = pb2[o];
        else if (o < 8)  bv = qb2[o - 4];
        else if (o == 8) bv = tb2[0];
        else if (o < 24) bv = ab2[(o - 9) % 3];
        else if (o < 39) bv = ab2[3 + (o - 24) % 3];
        else             bv = 0.f;
        bout[o] = bv;
      }
    }
  } else {
    int i = (b - 1024) * 256 + t;   // 0 .. 2621439
    int n = i >> 6, k = i & 63;
    xpad[i] = (k < 29) ? f2bf(x[(size_t)n * 29 + k]) : (ushort_t)0;
  }
}

// ---------------------------------------------------------------------------
// GAT aggregation with fused scores — unchanged from round 5.
// ---------------------------------------------------------------------------
template <bool POOL>
__global__ __launch_bounds__(256) void k_agg(
    ushort_t* __restrict__ h, const float* __restrict__ a_s,
    const float* __restrict__ a_d, const float* __restrict__ eattr,
    const float* __restrict__ sce, const float* __restrict__ bvec,
    ushort_t* __restrict__ gmean) {
  int g0 = blockIdx.x * 2;
  int t = threadIdx.x;
  __shared__ uint2 shs[1280];
  __shared__ float sal[400];
  __shared__ float sss[2][5][8], ssd[2][5][8];
  const uint2* src = (const uint2*)(h + (size_t)g0 * 2560);
#pragma unroll
  for (int i = 0; i < 5; ++i) shs[i * 256 + t] = src[i * 256 + t];
  if (t < 160) {
    int gi = t / 80, rem = t % 80;
    int nh = rem >> 1, which = rem & 1;
    int node = nh >> 3, hd = nh & 7;
    const float* av = (which ? a_d : a_s) + hd * 64;
    const uint2* p = src + gi * 640 + node * 128 + hd * 16;
    float c0 = 0.f, c1 = 0.f, c2 = 0.f, c3 = 0.f;
#pragma unroll
    for (int e = 0; e < 16; ++e) {
      uint2 u = p[e];
      c0 = fmaf(bf2f((ushort_t)(u.x & 0xffff)), av[e * 4 + 0], c0);
      c1 = fmaf(bf2f((ushort_t)(u.x >> 16)),    av[e * 4 + 1], c1);
      c2 = fmaf(bf2f((ushort_t)(u.y & 0xffff)), av[e * 4 + 2], c2);
      c3 = fmaf(bf2f((ushort_t)(u.y >> 16)),    av[e * 4 + 3], c3);
    }
    float tot = (c0 + c1) + (c2 + c3);
    if (which) ssd[gi][node][hd] = tot; else sss[gi][node][hd] = tot;
  }
  __syncthreads();
  if (t < 80) {
    int gi = t / 40, jh = t % 40;
    int j = jh >> 3, hd = jh & 7;
    int g = g0 + gi;
    float sdj = ssd[gi][j][hd];
    float ce = sce[hd];
    float lg[5], m = -1e30f;
#pragma unroll
    for (int i = 0; i < 5; ++i) {
      float l = sss[gi][i][hd] + sdj;
      if (i != j) l = fmaf(eattr[(size_t)g * 20 + i * 4 + (j > i ? j - 1 : j)], ce, l);
      l = l > 0.f ? l : 0.2f * l;
      lg[i] = l; m = fmaxf(m, l);
    }
    float s = 0.f;
#pragma unroll
    for (int i = 0; i < 5; ++i) { lg[i] = __expf(lg[i] - m); s += lg[i]; }
    float inv = 1.f / (s + 1e-16f);
#pragma unroll
    for (int i = 0; i < 5; ++i) sal[gi * 200 + j * 40 + i * 8 + hd] = lg[i] * inv;
  }
  __syncthreads();
  int gi = t >> 7, cq = t & 127;
  int c0 = cq * 4, hd = cq >> 4;
  float4 bb = *(const float4*)&bvec[c0];
  float hv[5][4];
#pragma unroll
  for (int i = 0; i < 5; ++i) {
    uint2 u = shs[gi * 640 + i * 128 + cq];
    hv[i][0] = bf2f((ushort_t)(u.x & 0xffff));
    hv[i][1] = bf2f((ushort_t)(u.x >> 16));
    hv[i][2] = bf2f((ushort_t)(u.y & 0xffff));
    hv[i][3] = bf2f((ushort_t)(u.y >> 16));
  }
  uint2* dst = (uint2*)(h + (size_t)g0 * 2560);
  float gs[4] = {0.f, 0.f, 0.f, 0.f};
#pragma unroll
  for (int j = 0; j < 5; ++j) {
    float o0 = bb.x, o1 = bb.y, o2 = bb.z, o3 = bb.w;
#pragma unroll
    for (int i = 0; i < 5; ++i) {
      float a = sal[gi * 200 + j * 40 + i * 8 + hd];
      o0 = fmaf(a, hv[i][0], o0); o1 = fmaf(a, hv[i][1], o1);
      o2 = fmaf(a, hv[i][2], o2); o3 = fmaf(a, hv[i][3], o3);
    }
    o0 = fmaxf(o0, 0.f); o1 = fmaxf(o1, 0.f);
    o2 = fmaxf(o2, 0.f); o3 = fmaxf(o3, 0.f);
    uint2 w;
    w.x = (uint_t)f2bf(o0) | ((uint_t)f2bf(o1) << 16);
    w.y = (uint_t)f2bf(o2) | ((uint_t)f2bf(o3) << 16);
    dst[gi * 640 + j * 128 + cq] = w;
    if (POOL) { gs[0] += o0; gs[1] += o1; gs[2] += o2; gs[3] += o3; }
  }
  if (POOL) {
    uint2 w;
    w.x = (uint_t)f2bf(gs[0] * 0.2f) | ((uint_t)f2bf(gs[1] * 0.2f) << 16);
    w.y = (uint_t)f2bf(gs[2] * 0.2f) | ((uint_t)f2bf(gs[3] * 0.2f) << 16);
    ((uint2*)gmean)[(size_t)(g0 + gi) * 128 + cq] = w;
  }
}

// ---------------------------------------------------------------------------
// bf16 MFMA GEMM body: 128x128 tile, BK=32, depth-3 prefetch (3 LDS buffers,
// counted vmcnt, raw barriers), XOR slot-swizzle on the K dimension:
// physical slot s_phys = s_log ^ (row&3) ^ ((row>>2)&3)  (involution).
// GLL keeps LDS linear; the GLOBAL source column is pre-swizzled (rule #21),
// reads apply the same XOR -> 8-way bank conflict becomes 2-way (free).
// EPI: 0 = bf16 out; 1 = f32 out; 2 = f32 out + bias + relu(col<320)
// ---------------------------------------------------------------------------
template <int EPI>
__device__ __forceinline__ void gemm_body(
    const ushort_t* __restrict__ A, const ushort_t* __restrict__ BT,
    const float* __restrict__ bias, void* __restrict__ Cv,
    int M, int N, int K, int m0, int n0, char* lds) {
  int t = threadIdx.x;
  int lane = t & 63;
  int wv = t >> 6;
  int wr = (wv >> 1) * 64, wc = (wv & 1) * 64;
  f32x4 acc[4][4] = {};
  // staging: 512 chunks of 16B per 8KB tile half; 2 A-chunks + 2 B-chunks/thread
  int ch0 = t, ch1 = t + 256;
  int row0 = ch0 >> 2, row1 = ch1 >> 2;
  int sw0 = (((ch0 & 3) ^ (row0 & 3) ^ ((row0 >> 2) & 3)) & 3) * 8;
  int sw1 = (((ch1 & 3) ^ (row1 & 3) ^ ((row1 >> 2) & 3)) & 3) * 8;
  // read-side swizzled K byte offset (row term depends only on lane&15)
  int ko2 = ((((lane >> 4) ^ (lane & 3) ^ ((lane >> 2) & 3)) & 3) * 16);
  const int nt = K >> 5;
#define STAGE(bi, kk0)                                                         \
  {                                                                            \
    char* ab = lds + (bi) * 16384;                                             \
    GLL(A + (size_t)(m0 + row0) * K + (kk0) + sw0, ab + ch0 * 16);             \
    GLL(A + (size_t)(m0 + row1) * K + (kk0) + sw1, ab + ch1 * 16);             \
    GLL(BT + (size_t)(n0 + row0) * K + (kk0) + sw0, ab + 8192 + ch0 * 16);     \
    GLL(BT + (size_t)(n0 + row1) * K + (kk0) + sw1, ab + 8192 + ch1 * 16);     \
  }
  STAGE(0, 0);
  if (nt > 1) STAGE(1, 32);
  for (int ts = 0; ts < nt; ++ts) {
    int bi = ts % 3;
    if (ts + 2 < nt) {
      STAGE((ts + 2) % 3, (ts + 2) * 32);
      asm volatile("s_waitcnt vmcnt(8)" ::: "memory");
    } else if (ts + 1 < nt) {
      asm volatile("s_waitcnt vmcnt(4)" ::: "memory");
    } else {
      asm volatile("s_waitcnt vmcnt(0)" ::: "memory");
    }
    __builtin_amdgcn_s_barrier();
    __builtin_amdgcn_sched_barrier(0);
    const char* ab = lds + bi * 16384;
    frag8 af[4], bfr[4];
#pragma unroll
    for (int m = 0; m < 4; ++m)
      af[m] = *(const frag8*)(ab + (wr + m * 16 + (lane & 15)) * 64 + ko2);
#pragma unroll
    for (int n = 0; n < 4; ++n)
      bfr[n] = *(const frag8*)(ab + 8192 + (wc + n * 16 + (lane & 15)) * 64 + ko2);
#pragma unroll
    for (int m = 0; m < 4; ++m)
#pragma unroll
      for (int n = 0; n < 4; ++n)
        acc[m][n] = __builtin_amdgcn_mfma_f32_16x16x32_bf16(af[m], bfr[n], acc[m][n], 0, 0, 0);
    __builtin_amdgcn_sched_barrier(0);
    __builtin_amdgcn_s_barrier();
  }
#undef STAGE
  int r4 = (lane >> 4) * 4;
  int cl = lane & 15;
#pragma unroll
  for (int m = 0; m < 4; ++m) {
#pragma unroll
    for (int n = 0; n < 4; ++n) {
      int col = n0 + wc + n * 16 + cl;
      float bb = (EPI == 2) ? bias[col] : 0.f;
#pragma unroll
      for (int r = 0; r < 4; ++r) {
        int row = m0 + wr + m * 16 + r4 + r;
        float v = acc[m][n][r] + bb;
        if (EPI == 2 && col < 320) v = fmaxf(v, 0.f);
        if (EPI == 0) ((ushort_t*)Cv)[(size_t)row * N + col] = f2bf(v);
        else          ((float*)Cv)[(size_t)row * N + col] = v;
      }
    }
  }
}

template <int EPI>
__global__ __launch_bounds__(256) void gemm_mfma(
    const ushort_t* __restrict__ A, const ushort_t* __restrict__ BT,
    const float* __restrict__ bias, void* __restrict__ Cv,
    int M, int N, int K, int nxblk) {
  __shared__ char lds[49152];
  int lid = xcd_swz(blockIdx.x, gridDim.x);
  gemm_body<EPI>(A, BT, bias, Cv, M, N, K, (lid / nxblk) * 128, (lid % nxblk) * 128, lds);
}

// Fused head GEMMs: blocks [0,320) -> ahid = h2 @ aw1topT^T (f32 out);
// blocks [320,576) -> hcat = gmean @ WcatT^T + bcat, relu(col<320).
__global__ __launch_bounds__(256) void k_hgemm(
    const ushort_t* __restrict__ h2, const ushort_t* __restrict__ aw1topT,
    float* __restrict__ ahid, const ushort_t* __restrict__ gmean,
    const ushort_t* __restrict__ WcatT, const float* __restrict__ bcat,
    float* __restrict__ hcat) {
  __shared__ char lds[49152];
  int bid = blockIdx.x;
  if (bid < 320) {
    int lid = xcd_swz(bid, 320);
    gemm_body<1>(h2, aw1topT, nullptr, ahid, NN, 128, DD, lid * 128, 0, lds);
  } else {
    int lid = xcd_swz(bid - 320, 256);
    gemm_body<2>(gmean, WcatT, bcat, hcat, GG, DD, DD, (lid >> 2) * 128, (lid & 3) * 128, lds);
  }
}

// ---------------------------------------------------------------------------
// Final heads — unchanged from round 5.
// ---------------------------------------------------------------------------
__global__ __launch_bounds__(256) void k_heads(
    const float* __restrict__ hcat, const float* __restrict__ ahid,
    const float* __restrict__ woutT, const float* __restrict__ bout,
    const float* __restrict__ alim, float* __restrict__ out) {
  int g0 = blockIdx.x * 4;
  int t = threadIdx.x;
  __shared__ float sbuf[4224];
  for (int i = t; i < 4224; i += 256) {
    int gi = i / 1056, r = i - gi * 1056;
    const float* grow = hcat + (size_t)(g0 + gi) * 512;
    float v = 0.f;
    if (r < 128)                  v = grow[r];
    else if (r >= 132 && r < 260) v = grow[128 + r - 132];
    else if (r >= 264 && r < 328) v = grow[256 + r - 264];
    else if (r >= 396) {
      int q = r - 396; int a = q / 132; int j = q - a * 132;
      if (j < 128)
        v = fmaxf(ahid[((size_t)(g0 + gi) * 5 + a) * 128 + j] + grow[320 + j], 0.f);
    }
    sbuf[i] = v;
  }
  __syncthreads();
  int gi = t >> 6, o = t & 63;
  int oc = o < 39 ? o : 39;
  int seg;
  if (oc < 4)       seg = 0;
  else if (oc < 8)  seg = 132;
  else if (oc == 8) seg = 264;
  else {
    int idx = (oc < 24) ? oc - 9 : oc - 24;
    seg = 396 + (idx / 3) * 132;
  }
  const float* ip = &sbuf[gi * 1056 + seg];
  float a0 = 0.f, a1 = 0.f, a2 = 0.f, a3 = 0.f;
#pragma unroll
  for (int j = 0; j < 128; j += 4) {
    a0 = fmaf(ip[j + 0], woutT[(j + 0) * 40 + oc], a0);
    a1 = fmaf(ip[j + 1], woutT[(j + 1) * 40 + oc], a1);
    a2 = fmaf(ip[j + 2], woutT[(j + 2) * 40 + oc], a2);
    a3 = fmaf(ip[j + 3], woutT[(j + 3) * 40 + oc], a3);
  }
  float res = (a0 + a1) + (a2 + a3) + bout[oc];
  if (o < 39) {
    if (o == 8)       res = 1.f / (1.f + __expf(-res));
    else if (o >= 24) res = 0.05f + 0.45f / (1.f + __expf(-res)) + 1e-6f;
    else if (o >= 9)  res = tanhf(res) * alim[(o - 9) % 3];
    out[(size_t)(g0 + gi) * 39 + o] = res;
  }
}

// ---------------------------------------------------------------------------
extern "C" void kernel_launch(void* const* d_in, const int* in_sizes, int n_in,
                              void* d_out, int out_size, void* d_ws, size_t ws_size,
                              hipStream_t stream) {
  const float* x     = (const float*)d_in[0];
  const float* eattr = (const float*)d_in[1];
  const float* W1  = (const float*)d_in[5];
  const float* as1 = (const float*)d_in[6];
  const float* ad1 = (const float*)d_in[7];
  const float* We1 = (const float*)d_in[8];
  const float* ae1 = (const float*)d_in[9];
  const float* b1  = (const float*)d_in[10];
  const float* W2  = (const float*)d_in[11];
  const float* as2 = (const float*)d_in[12];
  const float* ad2 = (const float*)d_in[13];
  const float* We2 = (const float*)d_in[14];
  const float* ae2 = (const float*)d_in[15];
  const float* b2  = (const float*)d_in[16];
  const float* pw1 = (const float*)d_in[17];
  const float* pb1 = (const float*)d_in[18];
  const float* pw2 = (const float*)d_in[19];
  const float* pb2 = (const float*)d_in[20];
  const float* qw1 = (const float*)d_in[21];
  const float* qb1 = (const float*)d_in[22];
  const float* qw2 = (const float*)d_in[23];
  const float* qb2 = (const float*)d_in[24];
  const float* aw1 = (const float*)d_in[25];
  const float* ab1 = (const float*)d_in[26];
  const float* aw2 = (const float*)d_in[27];
  const float* ab2 = (const float*)d_in[28];
  const float* tw1 = (const float*)d_in[29];
  const float* tb1 = (const float*)d_in[30];
  const float* tw2 = (const float*)d_in[31];
  const float* tb2 = (const float*)d_in[32];
  const float* alim = (const float*)d_in[33];

  const size_t BIGE = (size_t)NN * DD;
  char* p = (char*)d_ws;
  ushort_t* h1    = (ushort_t*)p; p += BIGE * 2;                 // 42MB (h1pre -> h1)
  ushort_t* h2    = (ushort_t*)p; p += BIGE * 2;                 // 42MB (h2pre -> h2)
  ushort_t* gmean = (ushort_t*)p; p += (size_t)GG * DD * 2;      // 8.4MB
  ushort_t* xpad  = (ushort_t*)p; p += (size_t)NN * 64 * 2;      // 5.2MB
  ushort_t* W1T   = (ushort_t*)p; p += (size_t)512 * 64 * 2;
  ushort_t* W2T   = (ushort_t*)p; p += (size_t)512 * 512 * 2;
  ushort_t* WcatT = (ushort_t*)p; p += (size_t)512 * 512 * 2;
  ushort_t* aw1topT = (ushort_t*)p; p += (size_t)128 * 512 * 2;
  float* bcat  = (float*)p; p += 512 * 4;
  float* sce   = (float*)p; p += 16 * 4;                          // [0,8)=L1 [8,16)=L2
  float* woutT = (float*)p; p += 5120 * 4;
  float* bout  = (float*)p; p += 40 * 4;
  float* ahid  = (float*)p; p += (size_t)NN * 128 * 4;            // 21MB
  float* hcat  = (float*)p;                                       // 16.8MB

  k_prep<<<1024 + 10240, 256, 0, stream>>>(
      x, W1, W2, pw1, qw1, tw1, aw1, pb1, qb1, tb1, ab1,
      We1, ae1, We2, ae2, pw2, pb2, qw2, qb2, tw2, tb2, aw2, ab2,
      xpad, W1T, W2T, WcatT, aw1topT, bcat, sce, woutT, bout);
  // --- layer 1 ---
  gemm_mfma<0><<<(NN / 128) * (DD / 128), 256, 0, stream>>>(
      xpad, W1T, nullptr, h1, NN, DD, 64, DD / 128);
  k_agg<false><<<GG / 2, 256, 0, stream>>>(h1, as1, ad1, eattr, sce, b1, nullptr);
  // --- layer 2 ---
  gemm_mfma<0><<<(NN / 128) * (DD / 128), 256, 0, stream>>>(
      h1, W2T, nullptr, h2, NN, DD, DD, DD / 128);
  k_agg<true><<<GG / 2, 256, 0, stream>>>(h2, as2, ad2, eattr, sce + 8, b2, gmean);
  // --- heads (fused: ahid + hcat in one launch) ---
  k_hgemm<<<320 + 256, 256, 0, stream>>>(h2, aw1topT, ahid, gmean, WcatT, bcat, hcat);
  k_heads<<<GG / 4, 256, 0, stream>>>(hcat, ahid, woutT, bout, alim, (float*)d_out);
}